// Round 1
// baseline (2595.289 us; speedup 1.0000x reference)
//
#include <hip/hip_runtime.h>
#include <math.h>

// ---- problem constants ----
#define B_      128
#define A_      24
#define N_      3072     // B_*A_
#define E_      73728
#define NLAYERS 4
#define MAXAT   103
#define EDGE_IN 581      // 2*256 + 9 + 60

// ---- workspace layout (float offsets) ----
#define OFF_COND   0         // [128][512]
#define OFF_LATIPS 65536     // [128][9]
#define OFF_NF     66688     // [3072][256]
#define OFF_NFMID  853120    // [3072][256]
#define OFF_AGG    1639552   // [3072][256]
#define OFF_WEMBT  2425984   // [103][256]
#define OFF_WCONDT 2452352   // [384][512]
#define OFF_WPROJT 2648960   // [256][256]
#define OFF_EW1T   2714496   // [4][581][256]
#define OFF_EW2T   3309440   // [4][256][256]
#define OFF_NW1T   3571584   // [4][512][256]
#define OFF_NW2T   4095872   // [4][256][256]
#define OFF_WTYPET 4358016   // [256][103]
// total 4384384 floats = 17.5 MB

// output offsets (floats): types | lattice | coords | nf
#define OUT_TYPES  0
#define OUT_LATT   316416
#define OUT_COORD  317568
#define OUT_NF     326784

__device__ __forceinline__ float silu_f(float x) { return x / (1.0f + __expf(-x)); }

// ---------------- weight transposes (coalesced-access layouts) ----------------
__global__ void k_prep(const float* w_emb, const float* w_cond, const float* w_proj,
                       const float* ew1, const float* ew2, const float* nw1, const float* nw2,
                       const float* w_type, float* ws) {
    int idx = blockIdx.x * blockDim.x + threadIdx.x;
    const int total = 1958400;
    if (idx >= total) return;
    int i = idx;
    if (i < 26368)  { int k = i / 256, h = i % 256; ws[OFF_WEMBT  + i] = w_emb[h * 103 + k]; return; }  i -= 26368;
    if (i < 196608) { int k = i / 512, h = i % 512; ws[OFF_WCONDT + i] = w_cond[h * 384 + k]; return; } i -= 196608;
    if (i < 65536)  { int k = i / 256, h = i % 256; ws[OFF_WPROJT + i] = w_proj[h * 256 + k]; return; } i -= 65536;
    if (i < 594944) { int l = i / 148736, r = i % 148736, k = r / 256, h = r % 256;
                      ws[OFF_EW1T + i] = ew1[(l * 256 + h) * 581 + k]; return; }                        i -= 594944;
    if (i < 262144) { int l = i / 65536, r = i % 65536, k = r / 256, h = r % 256;
                      ws[OFF_EW2T + i] = ew2[(l * 256 + h) * 256 + k]; return; }                        i -= 262144;
    if (i < 524288) { int l = i / 131072, r = i % 131072, k = r / 256, h = r % 256;
                      ws[OFF_NW1T + i] = nw1[(l * 256 + h) * 512 + k]; return; }                        i -= 524288;
    if (i < 262144) { int l = i / 65536, r = i % 65536, k = r / 256, h = r % 256;
                      ws[OFF_NW2T + i] = nw2[(l * 256 + h) * 256 + k]; return; }                        i -= 262144;
    { int k = i / 103, a = i % 103; ws[OFF_WTYPET + i] = w_type[a * 256 + k]; }
}

// ---------------- lat_ips = L @ L^T per graph ----------------
__global__ void k_latips(const float* lat, float* ws) {
    int idx = blockIdx.x * blockDim.x + threadIdx.x;
    if (idx >= B_ * 9) return;
    int b = idx / 9, r = idx % 9, i = r / 3, k = r % 3;
    const float* L = lat + b * 9;
    ws[OFF_LATIPS + idx] = L[i*3+0]*L[k*3+0] + L[i*3+1]*L[k*3+1] + L[i*3+2]*L[k*3+2];
}

// ---------------- cond = silu([t|text] @ w_cond^T + b_cond) ----------------
__global__ void k_cond(const float* t_in, const float* tx, const float* b_cond, float* ws) {
    __shared__ float s_in[384];
    int b = blockIdx.x, h = threadIdx.x;
    s_in[h] = t_in[b * 256 + h];
    if (h < 128) s_in[256 + h] = tx[b * 128 + h];
    __syncthreads();
    const float* W = ws + OFF_WCONDT;  // [384][512]
    float a0 = b_cond[h], a1 = b_cond[256 + h];
    for (int k = 0; k < 384; k++) {
        float v = s_in[k];
        a0 += v * W[k * 512 + h];
        a1 += v * W[k * 512 + 256 + h];
    }
    ws[OFF_COND + b * 512 + h]       = silu_f(a0);
    ws[OFF_COND + b * 512 + 256 + h] = silu_f(a1);
}

// ---------------- nf0 = atom_types @ w_emb^T + b_emb (8 nodes/block) ----------------
__global__ void k_embed(const float* at, const float* b_emb, float* ws) {
    __shared__ float s_at[8 * 103];
    int n0 = blockIdx.x * 8, tid = threadIdx.x;
    for (int i = tid; i < 8 * 103; i += 256) s_at[i] = at[n0 * 103 + i];
    __syncthreads();
    const float* W = ws + OFF_WEMBT;  // [103][256]
    float acc[8];
    float bb = b_emb[tid];
#pragma unroll
    for (int p = 0; p < 8; p++) acc[p] = bb;
    for (int k = 0; k < 103; k++) {
        float w = W[k * 256 + tid];
#pragma unroll
        for (int p = 0; p < 8; p++) acc[p] += s_at[p * 103 + k] * w;
    }
#pragma unroll
    for (int p = 0; p < 8; p++) ws[OFF_NF + (n0 + p) * 256 + tid] = acc[p];
}

// ---------------- FiLM: nf_mid = nf + silu(LN(nf@Wp^T+bp)*scale + shift) ----------------
__global__ void k_film(int l, const float* b_proj, const float* film_g, const float* film_b, float* ws) {
    __shared__ float nf8[8][256];
    __shared__ float red[4][8][2];
    int n0 = blockIdx.x * 8, h = threadIdx.x;
    for (int i = h; i < 2048; i += 256) nf8[i >> 8][i & 255] = ws[OFF_NF + n0 * 256 + i];
    __syncthreads();
    const float* W = ws + OFF_WPROJT;  // [256][256]
    float acc[8];
    float bp = b_proj[h];
#pragma unroll
    for (int p = 0; p < 8; p++) acc[p] = bp;
    for (int k = 0; k < 256; k += 4) {
        float w0 = W[k*256+h], w1 = W[(k+1)*256+h], w2 = W[(k+2)*256+h], w3 = W[(k+3)*256+h];
#pragma unroll
        for (int p = 0; p < 8; p++) {
            float4 v = *(const float4*)&nf8[p][k];
            acc[p] += v.x * w0 + v.y * w1 + v.z * w2 + v.w * w3;
        }
    }
    // block-wide mean/var per node
    float s[8], q[8];
#pragma unroll
    for (int p = 0; p < 8; p++) { s[p] = acc[p]; q[p] = acc[p] * acc[p]; }
#pragma unroll
    for (int o = 32; o > 0; o >>= 1) {
#pragma unroll
        for (int p = 0; p < 8; p++) { s[p] += __shfl_xor(s[p], o); q[p] += __shfl_xor(q[p], o); }
    }
    int lane = h & 63, wid = h >> 6;
    if (lane == 0) {
#pragma unroll
        for (int p = 0; p < 8; p++) { red[wid][p][0] = s[p]; red[wid][p][1] = q[p]; }
    }
    __syncthreads();
    float g = film_g[h], be = film_b[h];
#pragma unroll
    for (int p = 0; p < 8; p++) {
        float S = red[0][p][0] + red[1][p][0] + red[2][p][0] + red[3][p][0];
        float Q = red[0][p][1] + red[1][p][1] + red[2][p][1] + red[3][p][1];
        float mu = S * (1.0f / 256.0f);
        float var = Q * (1.0f / 256.0f) - mu * mu;
        float yn = (acc[p] - mu) * rsqrtf(var + 1e-5f) * g + be;
        int n = n0 + p, b = n / 24;
        float sc = ws[OFF_COND + b * 512 + h];
        float sh = ws[OFF_COND + b * 512 + 256 + h];
        ws[OFF_NFMID + n * 256 + h] = nf8[p][h] + silu_f(yn * sc + sh);
    }
}

// ---------------- edge MLP + aggregation: one block = (graph b, node i), 24 edges ----------------
__global__ void __launch_bounds__(256) k_edge(int l, const float* frac, const float* eb1, const float* eb2, float* ws) {
    __shared__ float nfj[24][256];
    __shared__ float ef1[24][256];
    __shared__ float dem[24][60];
    __shared__ float fc[24][3];
    __shared__ float latp[9];
    int b = blockIdx.x / 24, i = blockIdx.x % 24, h = threadIdx.x, n0 = b * 24;
    for (int idx = h; idx < 24 * 256; idx += 256) nfj[idx >> 8][idx & 255] = ws[OFF_NFMID + n0 * 256 + idx];
    for (int idx = h; idx < 72; idx += 256) fc[idx / 3][idx % 3] = frac[n0 * 3 + idx];
    if (h < 9) latp[h] = ws[OFF_LATIPS + b * 9 + h];
    __syncthreads();
    // demb: sin/cos(2*pi*f * ((fc[j]-fc[i]) mod 1)), k = d*10+f; [0:30)=sin, [30:60)=cos
    for (int idx = h; idx < 24 * 60; idx += 256) {
        int j = idx / 60, k = idx % 60;
        int kk = (k < 30) ? k : k - 30;
        int d = kk / 10, f = kk % 10;
        float fd = fc[j][d] - fc[i][d];
        fd -= floorf(fd);
        float ang = fd * (6.28318530717958647692f * (float)f);
        dem[j][k] = (k < 30) ? __sinf(ang) : __cosf(ang);
    }
    __syncthreads();

    const float* W1 = ws + OFF_EW1T + l * 148736;  // [581][256]
    // shared part across the 24 edges: nf[e0]=nfj[i] (cols 0..255) + lattice (cols 512..520)
    float p0 = eb1[l * 256 + h], p1 = 0.f, p2 = 0.f, p3 = 0.f;
    for (int k = 0; k < 256; k += 4) {
        p0 += nfj[i][k]     * W1[k*256+h];
        p1 += nfj[i][k + 1] * W1[(k+1)*256+h];
        p2 += nfj[i][k + 2] * W1[(k+2)*256+h];
        p3 += nfj[i][k + 3] * W1[(k+3)*256+h];
    }
#pragma unroll
    for (int r = 0; r < 9; r++) p0 += latp[r] * W1[(512 + r) * 256 + h];
    float part = p0 + p1 + p2 + p3;

    float acc[24];
#pragma unroll
    for (int j = 0; j < 24; j++) acc[j] = part;
    // nf[e1] part: cols 256..511 — 24-way W reuse, broadcast LDS reads
    for (int k = 0; k < 256; k += 4) {
        float w0 = W1[(256+k)*256+h], w1 = W1[(257+k)*256+h], w2 = W1[(258+k)*256+h], w3 = W1[(259+k)*256+h];
#pragma unroll
        for (int j = 0; j < 24; j++) {
            float4 v = *(const float4*)&nfj[j][k];
            acc[j] += v.x * w0 + v.y * w1 + v.z * w2 + v.w * w3;
        }
    }
    // demb part: cols 521..580
    for (int k = 0; k < 60; k += 2) {
        float w0 = W1[(521+k)*256+h], w1 = W1[(522+k)*256+h];
#pragma unroll
        for (int j = 0; j < 24; j++) acc[j] += dem[j][k] * w0 + dem[j][k+1] * w1;
    }
#pragma unroll
    for (int j = 0; j < 24; j++) ef1[j][h] = silu_f(acc[j]);
    __syncthreads();

    const float* W2 = ws + OFF_EW2T + l * 65536;  // [256][256]
    float acc2[24];
    float b2 = eb2[l * 256 + h];
#pragma unroll
    for (int j = 0; j < 24; j++) acc2[j] = b2;
    for (int k = 0; k < 256; k += 4) {
        float w0 = W2[k*256+h], w1 = W2[(k+1)*256+h], w2 = W2[(k+2)*256+h], w3 = W2[(k+3)*256+h];
#pragma unroll
        for (int j = 0; j < 24; j++) {
            float4 v = *(const float4*)&ef1[j][k];
            acc2[j] += v.x * w0 + v.y * w1 + v.z * w2 + v.w * w3;
        }
    }
    float aggv = 0.f;
#pragma unroll
    for (int j = 0; j < 24; j++) aggv += silu_f(acc2[j]);
    ws[OFF_AGG + (n0 + i) * 256 + h] = aggv * (1.0f / 24.0f);
}

// ---------------- node MLP + residual (8 nodes/block) ----------------
__global__ void k_node(int l, const float* nb1, const float* nb2, float* ws) {
    __shared__ float in2[8][512];
    __shared__ float hid[8][256];
    int n0 = blockIdx.x * 8, h = threadIdx.x;
    for (int idx = h; idx < 2048; idx += 256) in2[idx >> 8][idx & 255] = ws[OFF_NFMID + n0 * 256 + idx];
    for (int idx = h; idx < 2048; idx += 256) in2[idx >> 8][256 + (idx & 255)] = ws[OFF_AGG + n0 * 256 + idx];
    __syncthreads();
    const float* W1 = ws + OFF_NW1T + l * 131072;  // [512][256]
    float acc[8];
    float bb = nb1[l * 256 + h];
#pragma unroll
    for (int p = 0; p < 8; p++) acc[p] = bb;
    for (int k = 0; k < 512; k += 4) {
        float w0 = W1[k*256+h], w1 = W1[(k+1)*256+h], w2 = W1[(k+2)*256+h], w3 = W1[(k+3)*256+h];
#pragma unroll
        for (int p = 0; p < 8; p++) {
            float4 v = *(const float4*)&in2[p][k];
            acc[p] += v.x * w0 + v.y * w1 + v.z * w2 + v.w * w3;
        }
    }
#pragma unroll
    for (int p = 0; p < 8; p++) hid[p][h] = silu_f(acc[p]);
    __syncthreads();
    const float* W2 = ws + OFF_NW2T + l * 65536;  // [256][256]
    float a2[8];
    float b2 = nb2[l * 256 + h];
#pragma unroll
    for (int p = 0; p < 8; p++) a2[p] = b2;
    for (int k = 0; k < 256; k += 4) {
        float w0 = W2[k*256+h], w1 = W2[(k+1)*256+h], w2 = W2[(k+2)*256+h], w3 = W2[(k+3)*256+h];
#pragma unroll
        for (int p = 0; p < 8; p++) {
            float4 v = *(const float4*)&hid[p][k];
            a2[p] += v.x * w0 + v.y * w1 + v.z * w2 + v.w * w3;
        }
    }
#pragma unroll
    for (int p = 0; p < 8; p++) ws[OFF_NF + (n0 + p) * 256 + h] = in2[p][h] + silu_f(a2[p]);
}

// ---------------- outputs: atom_types_out, coords_out, nf copy ----------------
__global__ void k_out_node(const float* b_type, const float* w_coord, const float* ws, float* out) {
    __shared__ float nf8[8 * 256];
    int n0 = blockIdx.x * 8, tid = threadIdx.x;
    for (int idx = tid; idx < 2048; idx += 256) nf8[idx] = ws[OFF_NF + n0 * 256 + idx];
    __syncthreads();
    for (int idx = tid; idx < 2048; idx += 256) out[OUT_NF + n0 * 256 + idx] = nf8[idx];
    const float* WT = ws + OFF_WTYPET;  // [256][103]
    for (int idx = tid; idx < 8 * 103; idx += 256) {
        int p = idx / 103, a = idx % 103;
        float a0 = b_type[a], a1 = 0.f, a2 = 0.f, a3 = 0.f;
        for (int k = 0; k < 256; k += 4) {
            a0 += nf8[p * 256 + k]     * WT[k * 103 + a];
            a1 += nf8[p * 256 + k + 1] * WT[(k + 1) * 103 + a];
            a2 += nf8[p * 256 + k + 2] * WT[(k + 2) * 103 + a];
            a3 += nf8[p * 256 + k + 3] * WT[(k + 3) * 103 + a];
        }
        out[OUT_TYPES + (n0 + p) * 103 + a] = a0 + a1 + a2 + a3;
    }
    if (tid < 24) {
        int p = tid / 3, c = tid % 3;
        float a0 = 0.f;
        for (int k = 0; k < 256; k++) a0 += nf8[p * 256 + k] * w_coord[c * 256 + k];
        out[OUT_COORD + (n0 + p) * 3 + c] = a0;
    }
}

// ---------------- lattice_out = (mean(nf) @ w_latt^T).reshape(3,3) @ lattices ----------------
__global__ void k_out_graph(const float* lattices, const float* w_latt, const float* ws, float* out) {
    __shared__ float gf[256];
    __shared__ float lo[9];
    int b = blockIdx.x, h = threadIdx.x;
    float g = 0.f;
#pragma unroll
    for (int i = 0; i < 24; i++) g += ws[OFF_NF + (b * 24 + i) * 256 + h];
    gf[h] = g * (1.0f / 24.0f);
    __syncthreads();
    if (h < 9) {
        float a0 = 0.f;
        for (int k = 0; k < 256; k++) a0 += gf[k] * w_latt[h * 256 + k];
        lo[h] = a0;
    }
    __syncthreads();
    if (h < 9) {
        int i = h / 3, kk = h % 3;
        float a0 = 0.f;
#pragma unroll
        for (int j = 0; j < 3; j++) a0 += lo[i * 3 + j] * lattices[b * 9 + j * 3 + kk];
        out[OUT_LATT + b * 9 + h] = a0;
    }
}

extern "C" void kernel_launch(void* const* d_in, const int* in_sizes, int n_in,
                              void* d_out, int out_size, void* d_ws, size_t ws_size,
                              hipStream_t stream) {
    const float* atom_types = (const float*)d_in[0];
    const float* frac       = (const float*)d_in[1];
    const float* lattices   = (const float*)d_in[2];
    const float* t_in       = (const float*)d_in[3];
    const float* text       = (const float*)d_in[4];
    const float* w_emb      = (const float*)d_in[5];
    const float* b_emb      = (const float*)d_in[6];
    const float* w_cond     = (const float*)d_in[7];
    const float* b_cond     = (const float*)d_in[8];
    const float* w_proj     = (const float*)d_in[9];
    const float* b_proj     = (const float*)d_in[10];
    const float* film_g     = (const float*)d_in[11];
    const float* film_b     = (const float*)d_in[12];
    const float* ew1        = (const float*)d_in[13];
    const float* eb1        = (const float*)d_in[14];
    const float* ew2        = (const float*)d_in[15];
    const float* eb2        = (const float*)d_in[16];
    const float* nw1        = (const float*)d_in[17];
    const float* nb1        = (const float*)d_in[18];
    const float* nw2        = (const float*)d_in[19];
    const float* nb2        = (const float*)d_in[20];
    const float* w_coord    = (const float*)d_in[21];
    const float* w_latt     = (const float*)d_in[22];
    const float* w_type     = (const float*)d_in[23];
    const float* b_type     = (const float*)d_in[24];
    float* ws  = (float*)d_ws;
    float* out = (float*)d_out;

    k_prep<<<(1958400 + 255) / 256, 256, 0, stream>>>(w_emb, w_cond, w_proj, ew1, ew2, nw1, nw2, w_type, ws);
    k_latips<<<5, 256, 0, stream>>>(lattices, ws);
    k_cond<<<B_, 256, 0, stream>>>(t_in, text, b_cond, ws);
    k_embed<<<N_ / 8, 256, 0, stream>>>(atom_types, b_emb, ws);
    for (int l = 0; l < NLAYERS; l++) {
        k_film<<<N_ / 8, 256, 0, stream>>>(l, b_proj, film_g, film_b, ws);
        k_edge<<<N_, 256, 0, stream>>>(l, frac, eb1, eb2, ws);
        k_node<<<N_ / 8, 256, 0, stream>>>(l, nb1, nb2, ws);
    }
    k_out_node<<<N_ / 8, 256, 0, stream>>>(b_type, w_coord, ws, out);
    k_out_graph<<<B_, 256, 0, stream>>>(lattices, w_latt, ws, out);
}

// Round 2
// 840.221 us; speedup vs baseline: 3.0888x; 3.0888x over previous
//
#include <hip/hip_runtime.h>
#include <math.h>

// ---- problem constants ----
#define B_      128
#define A_      24
#define N_      3072     // B_*A_
#define NLAYERS 4

// ---- workspace layout (float-element offsets) ----
#define OFF_COND    0         // [128][512] f32
#define OFF_LATIPS  65536     // [128][9]   f32
#define OFF_LATW    66688     // [4][128][256] f32
#define OFF_NF      197760    // [3072][256] f32
#define OFF_NFMID   984192    // [3072][256] f32
#define OFF_AGG     1770624   // [3072][256] f32
#define OFF_PARTI   2557056   // [3072][256] f32
#define OFF_PARTJ   3343488   // [3072][256] f32
#define OFF_NFMIDH  4129920   // [3072][256] bf16 (ushort) -> 393216 float slots
#define OFF_WEMBT   4523136   // [103][256] f32
#define OFF_WCONDT  4549504   // [384][512] f32
#define OFF_WPROJT  4746112   // [256][256] f32
#define OFF_NW1T    4811648   // [4][512][256] f32
#define OFF_NW2T    5335936   // [4][256][256] f32
#define OFF_WTYPET  5598080   // [256][103] f32
#define OFF_W1LATT  5624448   // [4][9][256] f32
#define OFF_PW1A    5633664   // [4][8][16][64][8] bf16 -> 131072 float slots
#define OFF_PW1B    5764736   // same
#define OFF_PW1D    5895808   // [4][2][16][64][8] bf16 -> 32768 float slots
#define OFF_PW2     5928576   // [4][8][16][64][8] bf16
// end 6059648 floats = 23.1 MiB

// output offsets (floats): types | lattice | coords | nf
#define OUT_TYPES  0
#define OUT_LATT   316416
#define OUT_COORD  317568
#define OUT_NF     326784

typedef __attribute__((ext_vector_type(8))) short bf16x8;
typedef __attribute__((ext_vector_type(4))) float f32x4;

__device__ __forceinline__ float silu_f(float x) { return x / (1.0f + __expf(-x)); }
__device__ __forceinline__ unsigned short f2bf(float x) {
    unsigned int u = __float_as_uint(x);
    return (unsigned short)((u + 0x7FFFu + ((u >> 16) & 1u)) >> 16);
}
__device__ __forceinline__ float bf2f(unsigned short h) {
    return __uint_as_float(((unsigned int)h) << 16);
}

// ---------------- weight transposes + MFMA-fragment packs ----------------
__global__ void k_prep(const float* w_emb, const float* w_cond, const float* w_proj,
                       const float* ew1, const float* ew2, const float* nw1, const float* nw2,
                       const float* w_type, float* ws) {
    int idx = blockIdx.x * blockDim.x + threadIdx.x;
    unsigned short* pu = (unsigned short*)ws;
    int i = idx;
    if (i < 26368)  { int k = i / 256, h = i % 256; ws[OFF_WEMBT  + i] = w_emb[h * 103 + k]; return; }  i -= 26368;
    if (i < 196608) { int k = i / 512, h = i % 512; ws[OFF_WCONDT + i] = w_cond[h * 384 + k]; return; } i -= 196608;
    if (i < 65536)  { int k = i / 256, h = i % 256; ws[OFF_WPROJT + i] = w_proj[h * 256 + k]; return; } i -= 65536;
    if (i < 524288) { int l = i / 131072, r = i % 131072, k = r / 256, h = r % 256;
                      ws[OFF_NW1T + i] = nw1[((size_t)l * 256 + h) * 512 + k]; return; }               i -= 524288;
    if (i < 262144) { int l = i / 65536, r = i % 65536, k = r / 256, h = r % 256;
                      ws[OFF_NW2T + i] = nw2[((size_t)l * 256 + h) * 256 + k]; return; }               i -= 262144;
    if (i < 26368)  { int k = i / 103, a = i % 103; ws[OFF_WTYPET + i] = w_type[a * 256 + k]; return; } i -= 26368;
    if (i < 9216)   { int l = i / 2304, r = (i % 2304) / 256, h = i % 256;
                      ws[OFF_W1LATT + i] = ew1[((size_t)l * 256 + h) * 581 + 512 + r]; return; }        i -= 9216;
    if (i < 262144) { int l = i >> 16, r = i & 65535, ks = r >> 13, r2 = r & 8191,
                      nt = r2 >> 9, r3 = r2 & 511, lane = r3 >> 3, j = r3 & 7;
                      int k = ks * 32 + (lane >> 4) * 8 + j, n = nt * 16 + (lane & 15);
                      pu[(size_t)OFF_PW1A * 2 + i] = f2bf(ew1[((size_t)l * 256 + n) * 581 + k]); return; } i -= 262144;
    if (i < 262144) { int l = i >> 16, r = i & 65535, ks = r >> 13, r2 = r & 8191,
                      nt = r2 >> 9, r3 = r2 & 511, lane = r3 >> 3, j = r3 & 7;
                      int k = ks * 32 + (lane >> 4) * 8 + j, n = nt * 16 + (lane & 15);
                      pu[(size_t)OFF_PW1B * 2 + i] = f2bf(ew1[((size_t)l * 256 + n) * 581 + 256 + k]); return; } i -= 262144;
    if (i < 65536)  { int l = i >> 14, r = i & 16383, ks = r >> 13, r2 = r & 8191,
                      nt = r2 >> 9, r3 = r2 & 511, lane = r3 >> 3, j = r3 & 7;
                      int kp = ks * 32 + (lane >> 4) * 8 + j, n = nt * 16 + (lane & 15);
                      float v = (kp < 60) ? ew1[((size_t)l * 256 + n) * 581 + 521 + kp] : 0.0f;
                      pu[(size_t)OFF_PW1D * 2 + i] = f2bf(v); return; }                                  i -= 65536;
    if (i < 262144) { int l = i >> 16, r = i & 65535, ks = r >> 13, r2 = r & 8191,
                      nt = r2 >> 9, r3 = r2 & 511, lane = r3 >> 3, j = r3 & 7;
                      int k = ks * 32 + (lane >> 4) * 8 + j, n = nt * 16 + (lane & 15);
                      pu[(size_t)OFF_PW2 * 2 + i] = f2bf(ew2[((size_t)l * 256 + n) * 256 + k]); return; }
}

// ---------------- lat_ips = L @ L^T per graph ----------------
__global__ void k_latips(const float* lat, float* ws) {
    int idx = blockIdx.x * blockDim.x + threadIdx.x;
    if (idx >= B_ * 9) return;
    int b = idx / 9, r = idx % 9, i = r / 3, k = r % 3;
    const float* L = lat + b * 9;
    ws[OFF_LATIPS + idx] = L[i*3+0]*L[k*3+0] + L[i*3+1]*L[k*3+1] + L[i*3+2]*L[k*3+2];
}

// ---------------- latW[l][b][h] = sum_r latips[b][r] * W1lat[l][r][h] ----------------
__global__ void k_latw(float* ws) {
    __shared__ float lt[9];
    int b = blockIdx.x, h = threadIdx.x;
    if (h < 9) lt[h] = ws[OFF_LATIPS + b * 9 + h];
    __syncthreads();
    for (int l = 0; l < 4; l++) {
        float a = 0.f;
#pragma unroll
        for (int r = 0; r < 9; r++) a += lt[r] * ws[OFF_W1LATT + (l * 9 + r) * 256 + h];
        ws[OFF_LATW + (size_t)(l * 128 + b) * 256 + h] = a;
    }
}

// ---------------- cond = silu([t|text] @ w_cond^T + b_cond) ----------------
__global__ void k_cond(const float* t_in, const float* tx, const float* b_cond, float* ws) {
    __shared__ float s_in[384];
    int b = blockIdx.x, h = threadIdx.x;
    s_in[h] = t_in[b * 256 + h];
    if (h < 128) s_in[256 + h] = tx[b * 128 + h];
    __syncthreads();
    const float* W = ws + OFF_WCONDT;  // [384][512]
    float a0 = b_cond[h], a1 = b_cond[256 + h];
    for (int k = 0; k < 384; k++) {
        float v = s_in[k];
        a0 += v * W[k * 512 + h];
        a1 += v * W[k * 512 + 256 + h];
    }
    ws[OFF_COND + b * 512 + h]       = silu_f(a0);
    ws[OFF_COND + b * 512 + 256 + h] = silu_f(a1);
}

// ---------------- nf0 = atom_types @ w_emb^T + b_emb ----------------
__global__ void k_embed(const float* at, const float* b_emb, float* ws) {
    __shared__ float s_at[8 * 103];
    int n0 = blockIdx.x * 8, tid = threadIdx.x;
    for (int i = tid; i < 8 * 103; i += 256) s_at[i] = at[n0 * 103 + i];
    __syncthreads();
    const float* W = ws + OFF_WEMBT;  // [103][256]
    float acc[8];
    float bb = b_emb[tid];
#pragma unroll
    for (int p = 0; p < 8; p++) acc[p] = bb;
    for (int k = 0; k < 103; k++) {
        float w = W[k * 256 + tid];
#pragma unroll
        for (int p = 0; p < 8; p++) acc[p] += s_at[p * 103 + k] * w;
    }
#pragma unroll
    for (int p = 0; p < 8; p++) ws[OFF_NF + (size_t)(n0 + p) * 256 + tid] = acc[p];
}

// ---------------- FiLM: nf_mid = nf + silu(LN(nf@Wp^T+bp)*scale + shift) ----------------
__global__ void k_film(int l, const float* b_proj, const float* film_g, const float* film_b, float* ws) {
    __shared__ float nf8[8][256];
    __shared__ float red[4][8][2];
    int n0 = blockIdx.x * 8, h = threadIdx.x;
    for (int i = h; i < 2048; i += 256) nf8[i >> 8][i & 255] = ws[OFF_NF + (size_t)n0 * 256 + i];
    __syncthreads();
    const float* W = ws + OFF_WPROJT;  // [256][256]
    float acc[8];
    float bp = b_proj[h];
#pragma unroll
    for (int p = 0; p < 8; p++) acc[p] = bp;
    for (int k = 0; k < 256; k += 4) {
        float w0 = W[k*256+h], w1 = W[(k+1)*256+h], w2 = W[(k+2)*256+h], w3 = W[(k+3)*256+h];
#pragma unroll
        for (int p = 0; p < 8; p++) {
            float4 v = *(const float4*)&nf8[p][k];
            acc[p] += v.x * w0 + v.y * w1 + v.z * w2 + v.w * w3;
        }
    }
    float s[8], q[8];
#pragma unroll
    for (int p = 0; p < 8; p++) { s[p] = acc[p]; q[p] = acc[p] * acc[p]; }
#pragma unroll
    for (int o = 32; o > 0; o >>= 1) {
#pragma unroll
        for (int p = 0; p < 8; p++) { s[p] += __shfl_xor(s[p], o); q[p] += __shfl_xor(q[p], o); }
    }
    int lane = h & 63, wid = h >> 6;
    if (lane == 0) {
#pragma unroll
        for (int p = 0; p < 8; p++) { red[wid][p][0] = s[p]; red[wid][p][1] = q[p]; }
    }
    __syncthreads();
    float g = film_g[h], be = film_b[h];
    unsigned short* nfh = (unsigned short*)ws + (size_t)OFF_NFMIDH * 2;
#pragma unroll
    for (int p = 0; p < 8; p++) {
        float S = red[0][p][0] + red[1][p][0] + red[2][p][0] + red[3][p][0];
        float Q = red[0][p][1] + red[1][p][1] + red[2][p][1] + red[3][p][1];
        float mu = S * (1.0f / 256.0f);
        float var = Q * (1.0f / 256.0f) - mu * mu;
        float yn = (acc[p] - mu) * rsqrtf(var + 1e-5f) * g + be;
        int n = n0 + p, b = n / 24;
        float sc = ws[OFF_COND + b * 512 + h];
        float sh = ws[OFF_COND + b * 512 + 256 + h];
        float outv = nf8[p][h] + silu_f(yn * sc + sh);
        ws[OFF_NFMID + (size_t)n * 256 + h] = outv;
        nfh[(size_t)n * 256 + h] = f2bf(outv);
    }
}

// ---------------- PartI/PartJ: per-node halves of the edge GEMM1 (MFMA) ----------------
__global__ void __launch_bounds__(256) k_part(int l, const float* eb1, float* ws) {
    __shared__ __align__(16) unsigned short s_a[16][264];
    int tid = threadIdx.x, w = tid >> 6, ln = tid & 63;
    int n0 = blockIdx.x * 16;
    const unsigned short* nfh = (const unsigned short*)ws + (size_t)OFF_NFMIDH * 2;
    for (int ch = tid; ch < 512; ch += 256) {
        int row = ch >> 5, c8 = ch & 31;
        *(uint4*)&s_a[row][c8 * 8] = *(const uint4*)&nfh[(size_t)(n0 + row) * 256 + c8 * 8];
    }
    __syncthreads();
    const unsigned short* wsu = (const unsigned short*)ws;
    for (int g = 0; g < 2; g++) {
        const unsigned short* pack = wsu + (size_t)(g ? OFF_PW1B : OFF_PW1A) * 2 + (size_t)l * 65536;
        f32x4 acc[4] = {};
        for (int ks = 0; ks < 8; ks++) {
            bf16x8 a = *(const bf16x8*)&s_a[ln & 15][ks * 32 + (ln >> 4) * 8];
#pragma unroll
            for (int nt = 0; nt < 4; nt++) {
                bf16x8 bf = *(const bf16x8*)&pack[((size_t)(ks * 16 + w * 4 + nt) * 64 + ln) * 8];
                acc[nt] = __builtin_amdgcn_mfma_f32_16x16x32_bf16(a, bf, acc[nt], 0, 0, 0);
            }
        }
#pragma unroll
        for (int nt = 0; nt < 4; nt++) {
            int col = w * 64 + nt * 16 + (ln & 15);
#pragma unroll
            for (int r = 0; r < 4; r++) {
                int row = 4 * (ln >> 4) + r;
                int n = n0 + row;
                float v = acc[nt][r];
                if (g == 0) {
                    int gb = n / 24;
                    v += eb1[l * 256 + col] + ws[OFF_LATW + (size_t)(l * 128 + gb) * 256 + col];
                    ws[OFF_PARTI + (size_t)n * 256 + col] = v;
                } else {
                    ws[OFF_PARTJ + (size_t)n * 256 + col] = v;
                }
            }
        }
    }
}

// ---------------- fused edge pipeline: demb GEMM + add + silu + GEMM2 + silu + agg ----------------
__global__ void __launch_bounds__(256) k_edge(int l, const float* frac, const float* eb2, float* ws) {
    __shared__ __align__(16) unsigned short s_demb[48][72];
    __shared__ __align__(16) unsigned short s_ef1[48][264];
    __shared__ float s_pI[2][256];
    __shared__ float s_pJ[24][256];
    __shared__ float s_fc[24][3];
    int tid = threadIdx.x, w = tid >> 6, ln = tid & 63;
    int b = blockIdx.x / 12, c = blockIdx.x % 12;
    int i0 = c * 2;

    for (int idx = tid; idx < 72; idx += 256) s_fc[idx / 3][idx % 3] = frac[b * 72 + idx];
    {
        const float4* srcJ = (const float4*)(ws + OFF_PARTJ + (size_t)b * 24 * 256);
        float4* dstJ = (float4*)&s_pJ[0][0];
        for (int idx = tid; idx < 1536; idx += 256) dstJ[idx] = srcJ[idx];
        const float4* srcI = (const float4*)(ws + OFF_PARTI + (size_t)(b * 24 + i0) * 256);
        float4* dstI = (float4*)&s_pI[0][0];
        if (tid < 128) dstI[tid] = srcI[tid];
    }
    __syncthreads();
    // demb[row=e_loc][k] bf16, k 60..63 zero-padded (64..71 dead pad)
    for (int idx = tid; idx < 48 * 72; idx += 256) {
        int row = idx / 72, k = idx % 72;
        unsigned short v = 0;
        if (k < 60) {
            int kk = (k < 30) ? k : k - 30;
            int d = kk / 10, f = kk % 10;
            int hi = (row >= 24);
            int j = row - (hi ? 24 : 0);
            float fd = s_fc[j][d] - s_fc[i0 + hi][d];
            fd -= floorf(fd);
            float ang = fd * (6.283185307179586f * (float)f);
            v = f2bf((k < 30) ? __sinf(ang) : __cosf(ang));
        }
        s_demb[row][k] = v;
    }
    __syncthreads();

    const unsigned short* wsu = (const unsigned short*)ws;
    // GEMM1: [48 x 64] @ [64 x 256]
    const unsigned short* pw1d = wsu + (size_t)OFF_PW1D * 2 + (size_t)l * 16384;
    f32x4 acc1[3][4] = {};
    for (int ks = 0; ks < 2; ks++) {
        bf16x8 a[3];
#pragma unroll
        for (int mt = 0; mt < 3; mt++)
            a[mt] = *(const bf16x8*)&s_demb[mt * 16 + (ln & 15)][ks * 32 + (ln >> 4) * 8];
#pragma unroll
        for (int nt = 0; nt < 4; nt++) {
            bf16x8 bf = *(const bf16x8*)&pw1d[((size_t)(ks * 16 + w * 4 + nt) * 64 + ln) * 8];
#pragma unroll
            for (int mt = 0; mt < 3; mt++)
                acc1[mt][nt] = __builtin_amdgcn_mfma_f32_16x16x32_bf16(a[mt], bf, acc1[mt][nt], 0, 0, 0);
        }
    }
#pragma unroll
    for (int mt = 0; mt < 3; mt++)
#pragma unroll
        for (int nt = 0; nt < 4; nt++) {
            int col = w * 64 + nt * 16 + (ln & 15);
#pragma unroll
            for (int r = 0; r < 4; r++) {
                int row = mt * 16 + 4 * (ln >> 4) + r;
                int hi = (row >= 24);
                int j = row - (hi ? 24 : 0);
                float v = acc1[mt][nt][r] + s_pI[hi][col] + s_pJ[j][col];
                s_ef1[row][col] = f2bf(silu_f(v));
            }
        }
    __syncthreads();
    // GEMM2: [48 x 256] @ [256 x 256]
    const unsigned short* pw2 = wsu + (size_t)OFF_PW2 * 2 + (size_t)l * 65536;
    f32x4 acc2[3][4] = {};
    for (int ks = 0; ks < 8; ks++) {
        bf16x8 a[3];
#pragma unroll
        for (int mt = 0; mt < 3; mt++)
            a[mt] = *(const bf16x8*)&s_ef1[mt * 16 + (ln & 15)][ks * 32 + (ln >> 4) * 8];
#pragma unroll
        for (int nt = 0; nt < 4; nt++) {
            bf16x8 bf = *(const bf16x8*)&pw2[((size_t)(ks * 16 + w * 4 + nt) * 64 + ln) * 8];
#pragma unroll
            for (int mt = 0; mt < 3; mt++)
                acc2[mt][nt] = __builtin_amdgcn_mfma_f32_16x16x32_bf16(a[mt], bf, acc2[mt][nt], 0, 0, 0);
        }
    }
    __syncthreads();  // all s_ef1 reads done before overwrite
#pragma unroll
    for (int nt = 0; nt < 4; nt++) {
        int col = w * 64 + nt * 16 + (ln & 15);
        float b2 = eb2[l * 256 + col];
#pragma unroll
        for (int mt = 0; mt < 3; mt++)
#pragma unroll
            for (int r = 0; r < 4; r++) {
                int row = mt * 16 + 4 * (ln >> 4) + r;
                s_ef1[row][col] = f2bf(silu_f(acc2[mt][nt][r] + b2));
            }
    }
    __syncthreads();
    // aggregate 24 edges per i-group
    for (int idx = tid; idx < 512; idx += 256) {
        int hi = idx >> 8, col = idx & 255;
        float s = 0.f;
#pragma unroll
        for (int j = 0; j < 24; j++) s += bf2f(s_ef1[hi * 24 + j][col]);
        ws[OFF_AGG + (size_t)(b * 24 + i0 + hi) * 256 + col] = s * (1.0f / 24.0f);
    }
}

// ---------------- node MLP + residual (8 nodes/block) ----------------
__global__ void k_node(int l, const float* nb1, const float* nb2, float* ws) {
    __shared__ float in2[8][512];
    __shared__ float hid[8][256];
    int n0 = blockIdx.x * 8, h = threadIdx.x;
    for (int idx = h; idx < 2048; idx += 256) in2[idx >> 8][idx & 255] = ws[OFF_NFMID + (size_t)n0 * 256 + idx];
    for (int idx = h; idx < 2048; idx += 256) in2[idx >> 8][256 + (idx & 255)] = ws[OFF_AGG + (size_t)n0 * 256 + idx];
    __syncthreads();
    const float* W1 = ws + OFF_NW1T + (size_t)l * 131072;  // [512][256]
    float acc[8];
    float bb = nb1[l * 256 + h];
#pragma unroll
    for (int p = 0; p < 8; p++) acc[p] = bb;
    for (int k = 0; k < 512; k += 4) {
        float w0 = W1[k*256+h], w1 = W1[(k+1)*256+h], w2 = W1[(k+2)*256+h], w3 = W1[(k+3)*256+h];
#pragma unroll
        for (int p = 0; p < 8; p++) {
            float4 v = *(const float4*)&in2[p][k];
            acc[p] += v.x * w0 + v.y * w1 + v.z * w2 + v.w * w3;
        }
    }
#pragma unroll
    for (int p = 0; p < 8; p++) hid[p][h] = silu_f(acc[p]);
    __syncthreads();
    const float* W2 = ws + OFF_NW2T + (size_t)l * 65536;  // [256][256]
    float a2[8];
    float b2 = nb2[l * 256 + h];
#pragma unroll
    for (int p = 0; p < 8; p++) a2[p] = b2;
    for (int k = 0; k < 256; k += 4) {
        float w0 = W2[k*256+h], w1 = W2[(k+1)*256+h], w2 = W2[(k+2)*256+h], w3 = W2[(k+3)*256+h];
#pragma unroll
        for (int p = 0; p < 8; p++) {
            float4 v = *(const float4*)&hid[p][k];
            a2[p] += v.x * w0 + v.y * w1 + v.z * w2 + v.w * w3;
        }
    }
#pragma unroll
    for (int p = 0; p < 8; p++) ws[OFF_NF + (size_t)(n0 + p) * 256 + h] = in2[p][h] + silu_f(a2[p]);
}

// ---------------- outputs: atom_types_out, coords_out, nf copy ----------------
__global__ void k_out_node(const float* b_type, const float* w_coord, const float* ws, float* out) {
    __shared__ float nf8[8 * 256];
    int n0 = blockIdx.x * 8, tid = threadIdx.x;
    for (int idx = tid; idx < 2048; idx += 256) nf8[idx] = ws[OFF_NF + (size_t)n0 * 256 + idx];
    __syncthreads();
    for (int idx = tid; idx < 2048; idx += 256) out[OUT_NF + (size_t)n0 * 256 + idx] = nf8[idx];
    const float* WT = ws + OFF_WTYPET;  // [256][103]
    for (int idx = tid; idx < 8 * 103; idx += 256) {
        int p = idx / 103, a = idx % 103;
        float a0 = b_type[a], a1 = 0.f, a2 = 0.f, a3 = 0.f;
        for (int k = 0; k < 256; k += 4) {
            a0 += nf8[p * 256 + k]     * WT[k * 103 + a];
            a1 += nf8[p * 256 + k + 1] * WT[(k + 1) * 103 + a];
            a2 += nf8[p * 256 + k + 2] * WT[(k + 2) * 103 + a];
            a3 += nf8[p * 256 + k + 3] * WT[(k + 3) * 103 + a];
        }
        out[OUT_TYPES + (size_t)(n0 + p) * 103 + a] = a0 + a1 + a2 + a3;
    }
    if (tid < 24) {
        int p = tid / 3, c = tid % 3;
        float a0 = 0.f;
        for (int k = 0; k < 256; k++) a0 += nf8[p * 256 + k] * w_coord[c * 256 + k];
        out[OUT_COORD + (size_t)(n0 + p) * 3 + c] = a0;
    }
}

// ---------------- lattice_out ----------------
__global__ void k_out_graph(const float* lattices, const float* w_latt, const float* ws, float* out) {
    __shared__ float gf[256];
    __shared__ float lo[9];
    int b = blockIdx.x, h = threadIdx.x;
    float g = 0.f;
#pragma unroll
    for (int i = 0; i < 24; i++) g += ws[OFF_NF + (size_t)(b * 24 + i) * 256 + h];
    gf[h] = g * (1.0f / 24.0f);
    __syncthreads();
    if (h < 9) {
        float a0 = 0.f;
        for (int k = 0; k < 256; k++) a0 += gf[k] * w_latt[h * 256 + k];
        lo[h] = a0;
    }
    __syncthreads();
    if (h < 9) {
        int i = h / 3, kk = h % 3;
        float a0 = 0.f;
#pragma unroll
        for (int j = 0; j < 3; j++) a0 += lo[i * 3 + j] * lattices[b * 9 + j * 3 + kk];
        out[OUT_LATT + b * 9 + h] = a0;
    }
}

extern "C" void kernel_launch(void* const* d_in, const int* in_sizes, int n_in,
                              void* d_out, int out_size, void* d_ws, size_t ws_size,
                              hipStream_t stream) {
    const float* atom_types = (const float*)d_in[0];
    const float* frac       = (const float*)d_in[1];
    const float* lattices   = (const float*)d_in[2];
    const float* t_in       = (const float*)d_in[3];
    const float* text       = (const float*)d_in[4];
    const float* w_emb      = (const float*)d_in[5];
    const float* b_emb      = (const float*)d_in[6];
    const float* w_cond     = (const float*)d_in[7];
    const float* b_cond     = (const float*)d_in[8];
    const float* w_proj     = (const float*)d_in[9];
    const float* b_proj     = (const float*)d_in[10];
    const float* film_g     = (const float*)d_in[11];
    const float* film_b     = (const float*)d_in[12];
    const float* ew1        = (const float*)d_in[13];
    const float* eb1        = (const float*)d_in[14];
    const float* ew2        = (const float*)d_in[15];
    const float* eb2        = (const float*)d_in[16];
    const float* nw1        = (const float*)d_in[17];
    const float* nb1        = (const float*)d_in[18];
    const float* nw2        = (const float*)d_in[19];
    const float* nb2        = (const float*)d_in[20];
    const float* w_coord    = (const float*)d_in[21];
    const float* w_latt     = (const float*)d_in[22];
    const float* w_type     = (const float*)d_in[23];
    const float* b_type     = (const float*)d_in[24];
    float* ws  = (float*)d_ws;
    float* out = (float*)d_out;

    k_prep<<<7666, 256, 0, stream>>>(w_emb, w_cond, w_proj, ew1, ew2, nw1, nw2, w_type, ws);
    k_latips<<<5, 256, 0, stream>>>(lattices, ws);
    k_latw<<<B_, 256, 0, stream>>>(ws);
    k_cond<<<B_, 256, 0, stream>>>(t_in, text, b_cond, ws);
    k_embed<<<N_ / 8, 256, 0, stream>>>(atom_types, b_emb, ws);
    for (int l = 0; l < NLAYERS; l++) {
        k_film<<<N_ / 8, 256, 0, stream>>>(l, b_proj, film_g, film_b, ws);
        k_part<<<N_ / 16, 256, 0, stream>>>(l, eb1, ws);
        k_edge<<<N_ * 12 / 24, 256, 0, stream>>>(l, frac, eb2, ws);
        k_node<<<N_ / 8, 256, 0, stream>>>(l, nb1, nb2, ws);
    }
    k_out_node<<<N_ / 8, 256, 0, stream>>>(b_type, w_coord, ws, out);
    k_out_graph<<<B_, 256, 0, stream>>>(lattices, w_latt, ws, out);
}

// Round 3
// 524.877 us; speedup vs baseline: 4.9446x; 1.6008x over previous
//
#include <hip/hip_runtime.h>
#include <math.h>

// ---- problem constants ----
#define B_      128
#define A_      24
#define N_      3072     // B_*A_
#define NLAYERS 4

// ---- workspace layout (float-element offsets) ----
#define OFF_COND    0         // [128][512] f32
#define OFF_LATIPS  65536     // [128][9]   f32
#define OFF_LATW    66688     // [4][128][256] f32
#define OFF_NF      197760    // [3072][256] f32
#define OFF_NFH     984192    // [3072][256] bf16
#define OFF_NFMID   1377408   // [3072][256] f32
#define OFF_NFMIDH  2163840   // [3072][256] bf16
#define OFF_AGGH    2557056   // [3072][256] bf16
#define OFF_PARTI   2950272   // [3072][256] f32
#define OFF_PARTJ   3736704   // [3072][256] f32
#define OFF_WEMBT   4523136   // [103][256] f32
#define OFF_WCONDT  4549504   // [384][512] f32
#define OFF_WTYPET  4746112   // [256][103] f32
#define OFF_W1LATT  4772480   // [4][9][256] f32
#define OFF_PW1A    4781696   // [4][8][16][64][8] bf16
#define OFF_PW1B    4912768   // same
#define OFF_PW1D    5043840   // [4][2][16][64][8] bf16
#define OFF_PW2     5076608   // [4][8][16][64][8] bf16
#define OFF_PWPROJ  5207680   // [8][16][64][8] bf16
#define OFF_PNW1    5240448   // [4][16][16][64][8] bf16
#define OFF_PNW2    5502592   // [4][8][16][64][8] bf16
// end 5633664 floats = 22.5 MiB

// output offsets (floats): types | lattice | coords | nf
#define OUT_TYPES  0
#define OUT_LATT   316416
#define OUT_COORD  317568
#define OUT_NF     326784

typedef __attribute__((ext_vector_type(8))) short bf16x8;
typedef __attribute__((ext_vector_type(4))) float f32x4;

__device__ __forceinline__ float silu_f(float x) { return x / (1.0f + __expf(-x)); }
__device__ __forceinline__ unsigned short f2bf(float x) {
    unsigned int u = __float_as_uint(x);
    return (unsigned short)((u + 0x7FFFu + ((u >> 16) & 1u)) >> 16);
}
__device__ __forceinline__ float bf2f(unsigned short h) {
    return __uint_as_float(((unsigned int)h) << 16);
}

// ---------------- weight transposes + MFMA-fragment packs ----------------
// pack layout: pack[((ks*16 + nt16)*64 + lane)*8 + j] = W[k][n],
//   k = ks*32 + (lane>>4)*8 + j,  n = nt16*16 + (lane&15)
__global__ void k_prep(const float* w_emb, const float* w_cond, const float* w_proj,
                       const float* ew1, const float* ew2, const float* nw1, const float* nw2,
                       const float* w_type, float* ws) {
    int idx = blockIdx.x * blockDim.x + threadIdx.x;
    unsigned short* pu = (unsigned short*)ws;
    int i = idx;
    if (i < 26368)  { int k = i / 256, h = i % 256; ws[OFF_WEMBT  + i] = w_emb[h * 103 + k]; return; }  i -= 26368;
    if (i < 196608) { int k = i / 512, h = i % 512; ws[OFF_WCONDT + i] = w_cond[h * 384 + k]; return; } i -= 196608;
    if (i < 26368)  { int k = i / 103, a = i % 103; ws[OFF_WTYPET + i] = w_type[a * 256 + k]; return; } i -= 26368;
    if (i < 9216)   { int l = i / 2304, r = (i % 2304) / 256, h = i % 256;
                      ws[OFF_W1LATT + i] = ew1[((size_t)l * 256 + h) * 581 + 512 + r]; return; }        i -= 9216;
    if (i < 262144) { int l = i >> 16, r = i & 65535, ks = r >> 13, r2 = r & 8191,
                      nt = r2 >> 9, r3 = r2 & 511, lane = r3 >> 3, j = r3 & 7;
                      int k = ks * 32 + (lane >> 4) * 8 + j, n = nt * 16 + (lane & 15);
                      pu[(size_t)OFF_PW1A * 2 + i] = f2bf(ew1[((size_t)l * 256 + n) * 581 + k]); return; } i -= 262144;
    if (i < 262144) { int l = i >> 16, r = i & 65535, ks = r >> 13, r2 = r & 8191,
                      nt = r2 >> 9, r3 = r2 & 511, lane = r3 >> 3, j = r3 & 7;
                      int k = ks * 32 + (lane >> 4) * 8 + j, n = nt * 16 + (lane & 15);
                      pu[(size_t)OFF_PW1B * 2 + i] = f2bf(ew1[((size_t)l * 256 + n) * 581 + 256 + k]); return; } i -= 262144;
    if (i < 65536)  { int l = i >> 14, r = i & 16383, ks = r >> 13, r2 = r & 8191,
                      nt = r2 >> 9, r3 = r2 & 511, lane = r3 >> 3, j = r3 & 7;
                      int kp = ks * 32 + (lane >> 4) * 8 + j, n = nt * 16 + (lane & 15);
                      float v = (kp < 60) ? ew1[((size_t)l * 256 + n) * 581 + 521 + kp] : 0.0f;
                      pu[(size_t)OFF_PW1D * 2 + i] = f2bf(v); return; }                                  i -= 65536;
    if (i < 262144) { int l = i >> 16, r = i & 65535, ks = r >> 13, r2 = r & 8191,
                      nt = r2 >> 9, r3 = r2 & 511, lane = r3 >> 3, j = r3 & 7;
                      int k = ks * 32 + (lane >> 4) * 8 + j, n = nt * 16 + (lane & 15);
                      pu[(size_t)OFF_PW2 * 2 + i] = f2bf(ew2[((size_t)l * 256 + n) * 256 + k]); return; } i -= 262144;
    if (i < 65536)  { int ks = i >> 13, r2 = i & 8191,
                      nt = r2 >> 9, r3 = r2 & 511, lane = r3 >> 3, j = r3 & 7;
                      int k = ks * 32 + (lane >> 4) * 8 + j, n = nt * 16 + (lane & 15);
                      pu[(size_t)OFF_PWPROJ * 2 + i] = f2bf(w_proj[(size_t)n * 256 + k]); return; }      i -= 65536;
    if (i < 524288) { int l = i >> 17, r = i & 131071, ks = r >> 13, r2 = r & 8191,
                      nt = r2 >> 9, r3 = r2 & 511, lane = r3 >> 3, j = r3 & 7;
                      int k = ks * 32 + (lane >> 4) * 8 + j, n = nt * 16 + (lane & 15);
                      pu[(size_t)OFF_PNW1 * 2 + i] = f2bf(nw1[((size_t)l * 256 + n) * 512 + k]); return; } i -= 524288;
    if (i < 262144) { int l = i >> 16, r = i & 65535, ks = r >> 13, r2 = r & 8191,
                      nt = r2 >> 9, r3 = r2 & 511, lane = r3 >> 3, j = r3 & 7;
                      int k = ks * 32 + (lane >> 4) * 8 + j, n = nt * 16 + (lane & 15);
                      pu[(size_t)OFF_PNW2 * 2 + i] = f2bf(nw2[((size_t)l * 256 + n) * 256 + k]); return; }
}

// ---------------- lat_ips = L @ L^T per graph ----------------
__global__ void k_latips(const float* lat, float* ws) {
    int idx = blockIdx.x * blockDim.x + threadIdx.x;
    if (idx >= B_ * 9) return;
    int b = idx / 9, r = idx % 9, i = r / 3, k = r % 3;
    const float* L = lat + b * 9;
    ws[OFF_LATIPS + idx] = L[i*3+0]*L[k*3+0] + L[i*3+1]*L[k*3+1] + L[i*3+2]*L[k*3+2];
}

// ---------------- latW[l][b][h] = sum_r latips[b][r] * W1lat[l][r][h] ----------------
__global__ void k_latw(float* ws) {
    __shared__ float lt[9];
    int b = blockIdx.x, h = threadIdx.x;
    if (h < 9) lt[h] = ws[OFF_LATIPS + b * 9 + h];
    __syncthreads();
    for (int l = 0; l < 4; l++) {
        float a = 0.f;
#pragma unroll
        for (int r = 0; r < 9; r++) a += lt[r] * ws[OFF_W1LATT + (l * 9 + r) * 256 + h];
        ws[OFF_LATW + (size_t)(l * 128 + b) * 256 + h] = a;
    }
}

// ---------------- cond = silu([t|text] @ w_cond^T + b_cond) ----------------
__global__ void k_cond(const float* t_in, const float* tx, const float* b_cond, float* ws) {
    __shared__ float s_in[384];
    int b = blockIdx.x, h = threadIdx.x;
    s_in[h] = t_in[b * 256 + h];
    if (h < 128) s_in[256 + h] = tx[b * 128 + h];
    __syncthreads();
    const float* W = ws + OFF_WCONDT;  // [384][512]
    float a0 = b_cond[h], a1 = b_cond[256 + h];
    for (int k = 0; k < 384; k++) {
        float v = s_in[k];
        a0 += v * W[k * 512 + h];
        a1 += v * W[k * 512 + 256 + h];
    }
    ws[OFF_COND + b * 512 + h]       = silu_f(a0);
    ws[OFF_COND + b * 512 + 256 + h] = silu_f(a1);
}

// ---------------- nf0 = atom_types @ w_emb^T + b_emb ----------------
__global__ void k_embed(const float* at, const float* b_emb, float* ws) {
    __shared__ float s_at[8 * 103];
    int n0 = blockIdx.x * 8, tid = threadIdx.x;
    for (int i = tid; i < 8 * 103; i += 256) s_at[i] = at[n0 * 103 + i];
    __syncthreads();
    const float* W = ws + OFF_WEMBT;  // [103][256]
    float acc[8];
    float bb = b_emb[tid];
#pragma unroll
    for (int p = 0; p < 8; p++) acc[p] = bb;
    for (int k = 0; k < 103; k++) {
        float w = W[k * 256 + tid];
#pragma unroll
        for (int p = 0; p < 8; p++) acc[p] += s_at[p * 103 + k] * w;
    }
    unsigned short* nfh = (unsigned short*)ws + (size_t)OFF_NFH * 2;
#pragma unroll
    for (int p = 0; p < 8; p++) {
        ws[OFF_NF + (size_t)(n0 + p) * 256 + tid] = acc[p];
        nfh[(size_t)(n0 + p) * 256 + tid] = f2bf(acc[p]);
    }
}

// ---------------- fused FiLM + PartI/PartJ (MFMA), 16 nodes/block ----------------
__global__ void __launch_bounds__(256) k_film(int l, const float* b_proj, const float* film_g,
                                              const float* film_b, float* ws) {
    __shared__ __align__(16) unsigned short s_a[16][264];
    __shared__ float s_c[16][260];
    __shared__ float s_mu[16], s_rs[16];
    int tid = threadIdx.x, w = tid >> 6, ln = tid & 63;
    int n0 = blockIdx.x * 16;
    const unsigned short* nfh = (const unsigned short*)ws + (size_t)OFF_NFH * 2;
#pragma unroll
    for (int t = 0; t < 2; t++) {
        int idx = tid + t * 256;
        int row = idx >> 5, c8 = idx & 31;
        *(uint4*)&s_a[row][c8 * 8] = *(const uint4*)&nfh[(size_t)(n0 + row) * 256 + c8 * 8];
    }
    __syncthreads();
    const unsigned short* wsu = (const unsigned short*)ws;
    // proj GEMM: [16 x 256] @ [256 x 256]
    const unsigned short* pwp = wsu + (size_t)OFF_PWPROJ * 2;
    f32x4 acc[4] = {};
    for (int ks = 0; ks < 8; ks++) {
        bf16x8 a = *(const bf16x8*)&s_a[ln & 15][ks * 32 + (ln >> 4) * 8];
#pragma unroll
        for (int nt = 0; nt < 4; nt++) {
            bf16x8 bf = *(const bf16x8*)&pwp[((size_t)(ks * 16 + w * 4 + nt) * 64 + ln) * 8];
            acc[nt] = __builtin_amdgcn_mfma_f32_16x16x32_bf16(a, bf, acc[nt], 0, 0, 0);
        }
    }
#pragma unroll
    for (int nt = 0; nt < 4; nt++) {
        int col = w * 64 + nt * 16 + (ln & 15);
        float bp = b_proj[col];
#pragma unroll
        for (int r = 0; r < 4; r++) s_c[4 * (ln >> 4) + r][col] = acc[nt][r] + bp;
    }
    __syncthreads();
    // row stats (LN): wave w handles rows w*4 .. w*4+3
    for (int r4 = 0; r4 < 4; r4++) {
        int row = w * 4 + r4;
        float s = 0.f, q = 0.f;
        for (int c = ln; c < 256; c += 64) { float v = s_c[row][c]; s += v; q += v * v; }
#pragma unroll
        for (int o = 1; o < 64; o <<= 1) { s += __shfl_xor(s, o); q += __shfl_xor(q, o); }
        if (ln == 0) {
            float mu = s * (1.0f / 256.0f);
            float var = q * (1.0f / 256.0f) - mu * mu;
            s_mu[row] = mu; s_rs[row] = rsqrtf(var + 1e-5f);
        }
    }
    __syncthreads();
    // FiLM epilogue, per-column thread
    float g = film_g[tid], bb = film_b[tid];
    unsigned short* nfmidh = (unsigned short*)ws + (size_t)OFF_NFMIDH * 2;
    for (int row = 0; row < 16; row++) {
        int n = n0 + row, b = n / 24;
        float sc = ws[OFF_COND + b * 512 + tid];
        float sh = ws[OFF_COND + b * 512 + 256 + tid];
        float yn = (s_c[row][tid] - s_mu[row]) * s_rs[row] * g + bb;
        float nf = ws[OFF_NF + (size_t)n * 256 + tid];
        float outv = nf + silu_f(yn * sc + sh);
        ws[OFF_NFMID + (size_t)n * 256 + tid] = outv;
        nfmidh[(size_t)n * 256 + tid] = f2bf(outv);
        s_a[row][tid] = f2bf(outv);
    }
    __syncthreads();
    // PartI/PartJ GEMMs from resident nfmid tile
    const unsigned short* pA = wsu + (size_t)OFF_PW1A * 2 + (size_t)l * 65536;
    const unsigned short* pB = wsu + (size_t)OFF_PW1B * 2 + (size_t)l * 65536;
    f32x4 aI[4] = {}, aJ[4] = {};
    for (int ks = 0; ks < 8; ks++) {
        bf16x8 a = *(const bf16x8*)&s_a[ln & 15][ks * 32 + (ln >> 4) * 8];
#pragma unroll
        for (int nt = 0; nt < 4; nt++) {
            bf16x8 bi = *(const bf16x8*)&pA[((size_t)(ks * 16 + w * 4 + nt) * 64 + ln) * 8];
            bf16x8 bj = *(const bf16x8*)&pB[((size_t)(ks * 16 + w * 4 + nt) * 64 + ln) * 8];
            aI[nt] = __builtin_amdgcn_mfma_f32_16x16x32_bf16(a, bi, aI[nt], 0, 0, 0);
            aJ[nt] = __builtin_amdgcn_mfma_f32_16x16x32_bf16(a, bj, aJ[nt], 0, 0, 0);
        }
    }
#pragma unroll
    for (int nt = 0; nt < 4; nt++) {
        int col = w * 64 + nt * 16 + (ln & 15);
#pragma unroll
        for (int r = 0; r < 4; r++) {
            int n = n0 + 4 * (ln >> 4) + r;
            ws[OFF_PARTI + (size_t)n * 256 + col] = aI[nt][r];
            ws[OFF_PARTJ + (size_t)n * 256 + col] = aJ[nt][r];
        }
    }
}

// ---------------- fused edge pipeline: demb GEMM + add + silu + GEMM2 + silu + agg ----------------
__global__ void __launch_bounds__(256) k_edge(int l, const float* frac, const float* eb1,
                                              const float* eb2, float* ws) {
    __shared__ __align__(16) unsigned short s_demb[48][72];
    __shared__ __align__(16) unsigned short s_ef1[48][264];
    __shared__ float s_pI[2][256];
    __shared__ float s_pJ[24][256];
    __shared__ float s_fc[24][3];
    int tid = threadIdx.x, w = tid >> 6, ln = tid & 63;
    int b = blockIdx.x / 12, c = blockIdx.x % 12;
    int i0 = c * 2;

    for (int idx = tid; idx < 72; idx += 256) s_fc[idx / 3][idx % 3] = frac[b * 72 + idx];
    {
        const float4* srcJ = (const float4*)(ws + OFF_PARTJ + (size_t)b * 24 * 256);
        float4* dstJ = (float4*)&s_pJ[0][0];
        for (int idx = tid; idx < 1536; idx += 256) dstJ[idx] = srcJ[idx];
        // s_pI = PartI + eb1 + latW (bias adds folded here)
        for (int idx = tid; idx < 512; idx += 256) {
            int hi = idx >> 8, col = idx & 255;
            s_pI[hi][col] = ws[OFF_PARTI + (size_t)(b * 24 + i0 + hi) * 256 + col]
                          + eb1[l * 256 + col]
                          + ws[OFF_LATW + (size_t)(l * 128 + b) * 256 + col];
        }
    }
    __syncthreads();
    // demb[row=e_loc][k] bf16, k 60..63 zero-padded
    for (int idx = tid; idx < 48 * 72; idx += 256) {
        int row = idx / 72, k = idx % 72;
        unsigned short v = 0;
        if (k < 60) {
            int kk = (k < 30) ? k : k - 30;
            int d = kk / 10, f = kk % 10;
            int hi = (row >= 24);
            int j = row - (hi ? 24 : 0);
            float fd = s_fc[j][d] - s_fc[i0 + hi][d];
            fd -= floorf(fd);
            float ang = fd * (6.283185307179586f * (float)f);
            v = f2bf((k < 30) ? __sinf(ang) : __cosf(ang));
        }
        s_demb[row][k] = v;
    }
    __syncthreads();

    const unsigned short* wsu = (const unsigned short*)ws;
    // GEMM1: [48 x 64] @ [64 x 256]
    const unsigned short* pw1d = wsu + (size_t)OFF_PW1D * 2 + (size_t)l * 16384;
    f32x4 acc1[3][4] = {};
    for (int ks = 0; ks < 2; ks++) {
        bf16x8 a[3];
#pragma unroll
        for (int mt = 0; mt < 3; mt++)
            a[mt] = *(const bf16x8*)&s_demb[mt * 16 + (ln & 15)][ks * 32 + (ln >> 4) * 8];
#pragma unroll
        for (int nt = 0; nt < 4; nt++) {
            bf16x8 bf = *(const bf16x8*)&pw1d[((size_t)(ks * 16 + w * 4 + nt) * 64 + ln) * 8];
#pragma unroll
            for (int mt = 0; mt < 3; mt++)
                acc1[mt][nt] = __builtin_amdgcn_mfma_f32_16x16x32_bf16(a[mt], bf, acc1[mt][nt], 0, 0, 0);
        }
    }
#pragma unroll
    for (int mt = 0; mt < 3; mt++)
#pragma unroll
        for (int nt = 0; nt < 4; nt++) {
            int col = w * 64 + nt * 16 + (ln & 15);
#pragma unroll
            for (int r = 0; r < 4; r++) {
                int row = mt * 16 + 4 * (ln >> 4) + r;
                int hi = (row >= 24);
                int j = row - (hi ? 24 : 0);
                float v = acc1[mt][nt][r] + s_pI[hi][col] + s_pJ[j][col];
                s_ef1[row][col] = f2bf(silu_f(v));
            }
        }
    __syncthreads();
    // GEMM2: [48 x 256] @ [256 x 256]
    const unsigned short* pw2 = wsu + (size_t)OFF_PW2 * 2 + (size_t)l * 65536;
    f32x4 acc2[3][4] = {};
    for (int ks = 0; ks < 8; ks++) {
        bf16x8 a[3];
#pragma unroll
        for (int mt = 0; mt < 3; mt++)
            a[mt] = *(const bf16x8*)&s_ef1[mt * 16 + (ln & 15)][ks * 32 + (ln >> 4) * 8];
#pragma unroll
        for (int nt = 0; nt < 4; nt++) {
            bf16x8 bf = *(const bf16x8*)&pw2[((size_t)(ks * 16 + w * 4 + nt) * 64 + ln) * 8];
#pragma unroll
            for (int mt = 0; mt < 3; mt++)
                acc2[mt][nt] = __builtin_amdgcn_mfma_f32_16x16x32_bf16(a[mt], bf, acc2[mt][nt], 0, 0, 0);
        }
    }
    __syncthreads();
#pragma unroll
    for (int nt = 0; nt < 4; nt++) {
        int col = w * 64 + nt * 16 + (ln & 15);
        float b2 = eb2[l * 256 + col];
#pragma unroll
        for (int mt = 0; mt < 3; mt++)
#pragma unroll
            for (int r = 0; r < 4; r++) {
                int row = mt * 16 + 4 * (ln >> 4) + r;
                s_ef1[row][col] = f2bf(silu_f(acc2[mt][nt][r] + b2));
            }
    }
    __syncthreads();
    // aggregate 24 edges per i-group -> bf16
    unsigned short* aggh = (unsigned short*)ws + (size_t)OFF_AGGH * 2;
    for (int idx = tid; idx < 512; idx += 256) {
        int hi = idx >> 8, col = idx & 255;
        float s = 0.f;
#pragma unroll
        for (int j = 0; j < 24; j++) s += bf2f(s_ef1[hi * 24 + j][col]);
        aggh[(size_t)(b * 24 + i0 + hi) * 256 + col] = f2bf(s * (1.0f / 24.0f));
    }
}

// ---------------- node MLP + residual (MFMA), 16 nodes/block ----------------
__global__ void __launch_bounds__(256) k_node(int l, const float* nb1, const float* nb2, float* ws) {
    __shared__ __align__(16) unsigned short s_a[16][536];
    __shared__ __align__(16) unsigned short s_h[16][264];
    int tid = threadIdx.x, w = tid >> 6, ln = tid & 63;
    int n0 = blockIdx.x * 16;
    const unsigned short* nfmidh = (const unsigned short*)ws + (size_t)OFF_NFMIDH * 2;
    const unsigned short* aggh   = (const unsigned short*)ws + (size_t)OFF_AGGH * 2;
#pragma unroll
    for (int t = 0; t < 2; t++) {
        int idx = tid + t * 256;
        int row = idx >> 5, c8 = idx & 31;
        *(uint4*)&s_a[row][c8 * 8]       = *(const uint4*)&nfmidh[(size_t)(n0 + row) * 256 + c8 * 8];
        *(uint4*)&s_a[row][256 + c8 * 8] = *(const uint4*)&aggh[(size_t)(n0 + row) * 256 + c8 * 8];
    }
    __syncthreads();
    const unsigned short* wsu = (const unsigned short*)ws;
    // GEMM1: [16 x 512] @ [512 x 256]
    const unsigned short* p1 = wsu + (size_t)OFF_PNW1 * 2 + (size_t)l * 131072;
    f32x4 acc[4] = {};
    for (int ks = 0; ks < 16; ks++) {
        bf16x8 a = *(const bf16x8*)&s_a[ln & 15][ks * 32 + (ln >> 4) * 8];
#pragma unroll
        for (int nt = 0; nt < 4; nt++) {
            bf16x8 bf = *(const bf16x8*)&p1[((size_t)(ks * 16 + w * 4 + nt) * 64 + ln) * 8];
            acc[nt] = __builtin_amdgcn_mfma_f32_16x16x32_bf16(a, bf, acc[nt], 0, 0, 0);
        }
    }
#pragma unroll
    for (int nt = 0; nt < 4; nt++) {
        int col = w * 64 + nt * 16 + (ln & 15);
        float b1 = nb1[l * 256 + col];
#pragma unroll
        for (int r = 0; r < 4; r++) s_h[4 * (ln >> 4) + r][col] = f2bf(silu_f(acc[nt][r] + b1));
    }
    __syncthreads();
    // GEMM2: [16 x 256] @ [256 x 256]
    const unsigned short* p2 = wsu + (size_t)OFF_PNW2 * 2 + (size_t)l * 65536;
    f32x4 a2[4] = {};
    for (int ks = 0; ks < 8; ks++) {
        bf16x8 a = *(const bf16x8*)&s_h[ln & 15][ks * 32 + (ln >> 4) * 8];
#pragma unroll
        for (int nt = 0; nt < 4; nt++) {
            bf16x8 bf = *(const bf16x8*)&p2[((size_t)(ks * 16 + w * 4 + nt) * 64 + ln) * 8];
            a2[nt] = __builtin_amdgcn_mfma_f32_16x16x32_bf16(a, bf, a2[nt], 0, 0, 0);
        }
    }
    unsigned short* nfh = (unsigned short*)ws + (size_t)OFF_NFH * 2;
#pragma unroll
    for (int nt = 0; nt < 4; nt++) {
        int col = w * 64 + nt * 16 + (ln & 15);
        float b2 = nb2[l * 256 + col];
#pragma unroll
        for (int r = 0; r < 4; r++) {
            int n = n0 + 4 * (ln >> 4) + r;
            float v = ws[OFF_NFMID + (size_t)n * 256 + col] + silu_f(a2[nt][r] + b2);
            ws[OFF_NF + (size_t)n * 256 + col] = v;
            nfh[(size_t)n * 256 + col] = f2bf(v);
        }
    }
}

// ---------------- outputs: atom_types_out, coords_out, nf copy ----------------
__global__ void k_out_node(const float* b_type, const float* w_coord, const float* ws, float* out) {
    __shared__ float nf8[8 * 256];
    int n0 = blockIdx.x * 8, tid = threadIdx.x;
    for (int idx = tid; idx < 2048; idx += 256) nf8[idx] = ws[OFF_NF + (size_t)n0 * 256 + idx];
    __syncthreads();
    for (int idx = tid; idx < 2048; idx += 256) out[OUT_NF + (size_t)n0 * 256 + idx] = nf8[idx];
    const float* WT = ws + OFF_WTYPET;  // [256][103]
    for (int idx = tid; idx < 8 * 103; idx += 256) {
        int p = idx / 103, a = idx % 103;
        float a0 = b_type[a], a1 = 0.f, a2 = 0.f, a3 = 0.f;
        for (int k = 0; k < 256; k += 4) {
            a0 += nf8[p * 256 + k]     * WT[k * 103 + a];
            a1 += nf8[p * 256 + k + 1] * WT[(k + 1) * 103 + a];
            a2 += nf8[p * 256 + k + 2] * WT[(k + 2) * 103 + a];
            a3 += nf8[p * 256 + k + 3] * WT[(k + 3) * 103 + a];
        }
        out[OUT_TYPES + (size_t)(n0 + p) * 103 + a] = a0 + a1 + a2 + a3;
    }
    if (tid < 24) {
        int p = tid / 3, c = tid % 3;
        float a0 = 0.f;
        for (int k = 0; k < 256; k++) a0 += nf8[p * 256 + k] * w_coord[c * 256 + k];
        out[OUT_COORD + (size_t)(n0 + p) * 3 + c] = a0;
    }
}

// ---------------- lattice_out ----------------
__global__ void k_out_graph(const float* lattices, const float* w_latt, const float* ws, float* out) {
    __shared__ float gf[256];
    __shared__ float lo[9];
    int b = blockIdx.x, h = threadIdx.x;
    float g = 0.f;
#pragma unroll
    for (int i = 0; i < 24; i++) g += ws[OFF_NF + (size_t)(b * 24 + i) * 256 + h];
    gf[h] = g * (1.0f / 24.0f);
    __syncthreads();
    if (h < 9) {
        float a0 = 0.f;
        for (int k = 0; k < 256; k++) a0 += gf[k] * w_latt[h * 256 + k];
        lo[h] = a0;
    }
    __syncthreads();
    if (h < 9) {
        int i = h / 3, kk = h % 3;
        float a0 = 0.f;
#pragma unroll
        for (int j = 0; j < 3; j++) a0 += lo[i * 3 + j] * lattices[b * 9 + j * 3 + kk];
        out[OUT_LATT + b * 9 + h] = a0;
    }
}

extern "C" void kernel_launch(void* const* d_in, const int* in_sizes, int n_in,
                              void* d_out, int out_size, void* d_ws, size_t ws_size,
                              hipStream_t stream) {
    const float* atom_types = (const float*)d_in[0];
    const float* frac       = (const float*)d_in[1];
    const float* lattices   = (const float*)d_in[2];
    const float* t_in       = (const float*)d_in[3];
    const float* text       = (const float*)d_in[4];
    const float* w_emb      = (const float*)d_in[5];
    const float* b_emb      = (const float*)d_in[6];
    const float* w_cond     = (const float*)d_in[7];
    const float* b_cond     = (const float*)d_in[8];
    const float* w_proj     = (const float*)d_in[9];
    const float* b_proj     = (const float*)d_in[10];
    const float* film_g     = (const float*)d_in[11];
    const float* film_b     = (const float*)d_in[12];
    const float* ew1        = (const float*)d_in[13];
    const float* eb1        = (const float*)d_in[14];
    const float* ew2        = (const float*)d_in[15];
    const float* eb2        = (const float*)d_in[16];
    const float* nw1        = (const float*)d_in[17];
    const float* nb1        = (const float*)d_in[18];
    const float* nw2        = (const float*)d_in[19];
    const float* nb2        = (const float*)d_in[20];
    const float* w_coord    = (const float*)d_in[21];
    const float* w_latt     = (const float*)d_in[22];
    const float* w_type     = (const float*)d_in[23];
    const float* b_type     = (const float*)d_in[24];
    float* ws  = (float*)d_ws;
    float* out = (float*)d_out;

    k_prep<<<7666, 256, 0, stream>>>(w_emb, w_cond, w_proj, ew1, ew2, nw1, nw2, w_type, ws);
    k_latips<<<5, 256, 0, stream>>>(lattices, ws);
    k_latw<<<B_, 256, 0, stream>>>(ws);
    k_cond<<<B_, 256, 0, stream>>>(t_in, text, b_cond, ws);
    k_embed<<<N_ / 8, 256, 0, stream>>>(atom_types, b_emb, ws);
    for (int l = 0; l < NLAYERS; l++) {
        k_film<<<N_ / 16, 256, 0, stream>>>(l, b_proj, film_g, film_b, ws);
        k_edge<<<N_ * 12 / 24, 256, 0, stream>>>(l, frac, eb1, eb2, ws);
        k_node<<<N_ / 16, 256, 0, stream>>>(l, nb1, nb2, ws);
    }
    k_out_node<<<N_ / 8, 256, 0, stream>>>(b_type, w_coord, ws, out);
    k_out_graph<<<B_, 256, 0, stream>>>(lattices, w_latt, ws, out);
}

// Round 4
// 408.193 us; speedup vs baseline: 6.3580x; 1.2859x over previous
//
#include <hip/hip_runtime.h>
#include <math.h>

// ---- problem constants ----
#define B_      128
#define A_      24
#define N_      3072     // B_*A_
#define NLAYERS 4

// ---- workspace layout (float-element offsets) ----
#define OFF_COND    0         // [128][512] f32
#define OFF_LATIPS  65536     // [128][9]   f32
#define OFF_LATW    66688     // [4][128][256] f32
#define OFF_NF      197760    // [3072][256] f32
#define OFF_NFH     984192    // [3072][256] bf16
#define OFF_NFMIDH  1377408   // [3072][256] bf16
#define OFF_AGGH    1770624   // [3072][256] bf16
#define OFF_PARTIH  2163840   // [3072][256] bf16 (incl. eb1+latW)
#define OFF_PARTJH  2557056   // [3072][256] bf16
#define OFF_WEMBT   2950272   // [103][256] f32
#define OFF_WCONDT  2976640   // [384][512] f32
#define OFF_WTYPET  3173248   // [256][103] f32
#define OFF_W1LATT  3199616   // [4][9][256] f32
#define OFF_PW1A    3208832   // [4][8][16][64][8] bf16
#define OFF_PW1B    3339904
#define OFF_PW1D    3470976   // [4][2][16][64][8] bf16
#define OFF_PW2     3503744   // [4][8][16][64][8] bf16
#define OFF_PWPROJ  3634816   // [8][16][64][8] bf16
#define OFF_PNW1    3667584   // [4][16][16][64][8] bf16
#define OFF_PNW2    3929728   // [4][8][16][64][8] bf16
// end 4060800 floats = 16.2 MiB

// output offsets (floats): types | lattice | coords | nf
#define OUT_TYPES  0
#define OUT_LATT   316416
#define OUT_COORD  317568
#define OUT_NF     326784

typedef __attribute__((ext_vector_type(8))) short bf16x8;
typedef __attribute__((ext_vector_type(4))) float f32x4;

__device__ __forceinline__ float silu_f(float x) { return x / (1.0f + __expf(-x)); }
__device__ __forceinline__ unsigned short f2bf(float x) {
    unsigned int u = __float_as_uint(x);
    return (unsigned short)((u + 0x7FFFu + ((u >> 16) & 1u)) >> 16);
}
__device__ __forceinline__ float bf2f(unsigned short h) {
    return __uint_as_float(((unsigned int)h) << 16);
}

// ---------------- weight transposes + MFMA-fragment packs ----------------
// pack layout: pack[((ks*16 + nt16)*64 + lane)*8 + j] = W[k][n],
//   k = ks*32 + (lane>>4)*8 + j,  n = nt16*16 + (lane&15)
__global__ void k_prep(const float* w_emb, const float* w_cond, const float* w_proj,
                       const float* ew1, const float* ew2, const float* nw1, const float* nw2,
                       const float* w_type, float* ws) {
    int idx = blockIdx.x * blockDim.x + threadIdx.x;
    unsigned short* pu = (unsigned short*)ws;
    int i = idx;
    if (i < 26368)  { int k = i / 256, h = i % 256; ws[OFF_WEMBT  + i] = w_emb[h * 103 + k]; return; }  i -= 26368;
    if (i < 196608) { int k = i / 512, h = i % 512; ws[OFF_WCONDT + i] = w_cond[h * 384 + k]; return; } i -= 196608;
    if (i < 26368)  { int k = i / 103, a = i % 103; ws[OFF_WTYPET + i] = w_type[a * 256 + k]; return; } i -= 26368;
    if (i < 9216)   { int l = i / 2304, r = (i % 2304) / 256, h = i % 256;
                      ws[OFF_W1LATT + i] = ew1[((size_t)l * 256 + h) * 581 + 512 + r]; return; }        i -= 9216;
    if (i < 262144) { int l = i >> 16, r = i & 65535, ks = r >> 13, r2 = r & 8191,
                      nt = r2 >> 9, r3 = r2 & 511, lane = r3 >> 3, j = r3 & 7;
                      int k = ks * 32 + (lane >> 4) * 8 + j, n = nt * 16 + (lane & 15);
                      pu[(size_t)OFF_PW1A * 2 + i] = f2bf(ew1[((size_t)l * 256 + n) * 581 + k]); return; } i -= 262144;
    if (i < 262144) { int l = i >> 16, r = i & 65535, ks = r >> 13, r2 = r & 8191,
                      nt = r2 >> 9, r3 = r2 & 511, lane = r3 >> 3, j = r3 & 7;
                      int k = ks * 32 + (lane >> 4) * 8 + j, n = nt * 16 + (lane & 15);
                      pu[(size_t)OFF_PW1B * 2 + i] = f2bf(ew1[((size_t)l * 256 + n) * 581 + 256 + k]); return; } i -= 262144;
    if (i < 65536)  { int l = i >> 14, r = i & 16383, ks = r >> 13, r2 = r & 8191,
                      nt = r2 >> 9, r3 = r2 & 511, lane = r3 >> 3, j = r3 & 7;
                      int kp = ks * 32 + (lane >> 4) * 8 + j, n = nt * 16 + (lane & 15);
                      float v = (kp < 60) ? ew1[((size_t)l * 256 + n) * 581 + 521 + kp] : 0.0f;
                      pu[(size_t)OFF_PW1D * 2 + i] = f2bf(v); return; }                                  i -= 65536;
    if (i < 262144) { int l = i >> 16, r = i & 65535, ks = r >> 13, r2 = r & 8191,
                      nt = r2 >> 9, r3 = r2 & 511, lane = r3 >> 3, j = r3 & 7;
                      int k = ks * 32 + (lane >> 4) * 8 + j, n = nt * 16 + (lane & 15);
                      pu[(size_t)OFF_PW2 * 2 + i] = f2bf(ew2[((size_t)l * 256 + n) * 256 + k]); return; } i -= 262144;
    if (i < 65536)  { int ks = i >> 13, r2 = i & 8191,
                      nt = r2 >> 9, r3 = r2 & 511, lane = r3 >> 3, j = r3 & 7;
                      int k = ks * 32 + (lane >> 4) * 8 + j, n = nt * 16 + (lane & 15);
                      pu[(size_t)OFF_PWPROJ * 2 + i] = f2bf(w_proj[(size_t)n * 256 + k]); return; }      i -= 65536;
    if (i < 524288) { int l = i >> 17, r = i & 131071, ks = r >> 13, r2 = r & 8191,
                      nt = r2 >> 9, r3 = r2 & 511, lane = r3 >> 3, j = r3 & 7;
                      int k = ks * 32 + (lane >> 4) * 8 + j, n = nt * 16 + (lane & 15);
                      pu[(size_t)OFF_PNW1 * 2 + i] = f2bf(nw1[((size_t)l * 256 + n) * 512 + k]); return; } i -= 524288;
    if (i < 262144) { int l = i >> 16, r = i & 65535, ks = r >> 13, r2 = r & 8191,
                      nt = r2 >> 9, r3 = r2 & 511, lane = r3 >> 3, j = r3 & 7;
                      int k = ks * 32 + (lane >> 4) * 8 + j, n = nt * 16 + (lane & 15);
                      pu[(size_t)OFF_PNW2 * 2 + i] = f2bf(nw2[((size_t)l * 256 + n) * 256 + k]); return; }
}

// ---------------- lat_ips = L @ L^T per graph ----------------
__global__ void k_latips(const float* lat, float* ws) {
    int idx = blockIdx.x * blockDim.x + threadIdx.x;
    if (idx >= B_ * 9) return;
    int b = idx / 9, r = idx % 9, i = r / 3, k = r % 3;
    const float* L = lat + b * 9;
    ws[OFF_LATIPS + idx] = L[i*3+0]*L[k*3+0] + L[i*3+1]*L[k*3+1] + L[i*3+2]*L[k*3+2];
}

// ---------------- latW[l][b][h] = sum_r latips[b][r] * W1lat[l][r][h] ----------------
__global__ void k_latw(float* ws) {
    __shared__ float lt[9];
    int b = blockIdx.x, h = threadIdx.x;
    if (h < 9) lt[h] = ws[OFF_LATIPS + b * 9 + h];
    __syncthreads();
    for (int l = 0; l < 4; l++) {
        float a = 0.f;
#pragma unroll
        for (int r = 0; r < 9; r++) a += lt[r] * ws[OFF_W1LATT + (l * 9 + r) * 256 + h];
        ws[OFF_LATW + (size_t)(l * 128 + b) * 256 + h] = a;
    }
}

// ---------------- cond = silu([t|text] @ w_cond^T + b_cond) ----------------
__global__ void k_cond(const float* t_in, const float* tx, const float* b_cond, float* ws) {
    __shared__ float s_in[384];
    int b = blockIdx.x, h = threadIdx.x;
    s_in[h] = t_in[b * 256 + h];
    if (h < 128) s_in[256 + h] = tx[b * 128 + h];
    __syncthreads();
    const float* W = ws + OFF_WCONDT;  // [384][512]
    float a0 = b_cond[h], a1 = b_cond[256 + h];
    for (int k = 0; k < 384; k++) {
        float v = s_in[k];
        a0 += v * W[k * 512 + h];
        a1 += v * W[k * 512 + 256 + h];
    }
    ws[OFF_COND + b * 512 + h]       = silu_f(a0);
    ws[OFF_COND + b * 512 + 256 + h] = silu_f(a1);
}

// ---------------- nf0 = atom_types @ w_emb^T + b_emb ----------------
__global__ void k_embed(const float* at, const float* b_emb, float* ws) {
    __shared__ float s_at[8 * 103];
    int n0 = blockIdx.x * 8, tid = threadIdx.x;
    for (int i = tid; i < 8 * 103; i += 256) s_at[i] = at[n0 * 103 + i];
    __syncthreads();
    const float* W = ws + OFF_WEMBT;  // [103][256]
    float acc[8];
    float bb = b_emb[tid];
#pragma unroll
    for (int p = 0; p < 8; p++) acc[p] = bb;
    for (int k = 0; k < 103; k++) {
        float w = W[k * 256 + tid];
#pragma unroll
        for (int p = 0; p < 8; p++) acc[p] += s_at[p * 103 + k] * w;
    }
    unsigned short* nfh = (unsigned short*)ws + (size_t)OFF_NFH * 2;
#pragma unroll
    for (int p = 0; p < 8; p++) {
        ws[OFF_NF + (size_t)(n0 + p) * 256 + tid] = acc[p];
        nfh[(size_t)(n0 + p) * 256 + tid] = f2bf(acc[p]);
    }
}

// ---------------- fused FiLM + PartI/PartJ (MFMA), 16 nodes/block ----------------
__global__ void __launch_bounds__(256) k_film(int l, const float* b_proj, const float* film_g,
                                              const float* film_b, const float* eb1, float* ws) {
    __shared__ __align__(16) unsigned short s_a[16][264];
    __shared__ float s_c[16][260];
    __shared__ float s_mu[16], s_rs[16];
    int tid = threadIdx.x, w = tid >> 6, ln = tid & 63;
    int n0 = blockIdx.x * 16;
    const unsigned short* nfh = (const unsigned short*)ws + (size_t)OFF_NFH * 2;
#pragma unroll
    for (int t = 0; t < 2; t++) {
        int idx = tid + t * 256;
        int row = idx >> 5, c8 = idx & 31;
        *(uint4*)&s_a[row][c8 * 8] = *(const uint4*)&nfh[(size_t)(n0 + row) * 256 + c8 * 8];
    }
    __syncthreads();
    const unsigned short* wsu = (const unsigned short*)ws;
    // proj GEMM: [16 x 256] @ [256 x 256]
    const unsigned short* pwp = wsu + (size_t)OFF_PWPROJ * 2;
    f32x4 acc[4] = {};
    for (int ks = 0; ks < 8; ks++) {
        bf16x8 a = *(const bf16x8*)&s_a[ln & 15][ks * 32 + (ln >> 4) * 8];
#pragma unroll
        for (int nt = 0; nt < 4; nt++) {
            bf16x8 bf = *(const bf16x8*)&pwp[((size_t)(ks * 16 + w * 4 + nt) * 64 + ln) * 8];
            acc[nt] = __builtin_amdgcn_mfma_f32_16x16x32_bf16(a, bf, acc[nt], 0, 0, 0);
        }
    }
#pragma unroll
    for (int nt = 0; nt < 4; nt++) {
        int col = w * 64 + nt * 16 + (ln & 15);
        float bp = b_proj[col];
#pragma unroll
        for (int r = 0; r < 4; r++) s_c[4 * (ln >> 4) + r][col] = acc[nt][r] + bp;
    }
    __syncthreads();
    // row stats (LN)
    for (int r4 = 0; r4 < 4; r4++) {
        int row = w * 4 + r4;
        float s = 0.f, q = 0.f;
        for (int c = ln; c < 256; c += 64) { float v = s_c[row][c]; s += v; q += v * v; }
#pragma unroll
        for (int o = 1; o < 64; o <<= 1) { s += __shfl_xor(s, o); q += __shfl_xor(q, o); }
        if (ln == 0) {
            float mu = s * (1.0f / 256.0f);
            float var = q * (1.0f / 256.0f) - mu * mu;
            s_mu[row] = mu; s_rs[row] = rsqrtf(var + 1e-5f);
        }
    }
    __syncthreads();
    // FiLM epilogue, per-column thread
    float g = film_g[tid], bb = film_b[tid];
    unsigned short* nfmidh = (unsigned short*)ws + (size_t)OFF_NFMIDH * 2;
    for (int row = 0; row < 16; row++) {
        int n = n0 + row, b = n / 24;
        float sc = ws[OFF_COND + b * 512 + tid];
        float sh = ws[OFF_COND + b * 512 + 256 + tid];
        float yn = (s_c[row][tid] - s_mu[row]) * s_rs[row] * g + bb;
        float nf = ws[OFF_NF + (size_t)n * 256 + tid];
        float outv = nf + silu_f(yn * sc + sh);
        unsigned short ob = f2bf(outv);
        nfmidh[(size_t)n * 256 + tid] = ob;
        s_a[row][tid] = ob;
    }
    __syncthreads();
    // PartI/PartJ GEMMs from resident nfmid tile
    const unsigned short* pA = wsu + (size_t)OFF_PW1A * 2 + (size_t)l * 65536;
    const unsigned short* pB = wsu + (size_t)OFF_PW1B * 2 + (size_t)l * 65536;
    f32x4 aI[4] = {}, aJ[4] = {};
    for (int ks = 0; ks < 8; ks++) {
        bf16x8 a = *(const bf16x8*)&s_a[ln & 15][ks * 32 + (ln >> 4) * 8];
#pragma unroll
        for (int nt = 0; nt < 4; nt++) {
            bf16x8 bi = *(const bf16x8*)&pA[((size_t)(ks * 16 + w * 4 + nt) * 64 + ln) * 8];
            bf16x8 bj = *(const bf16x8*)&pB[((size_t)(ks * 16 + w * 4 + nt) * 64 + ln) * 8];
            aI[nt] = __builtin_amdgcn_mfma_f32_16x16x32_bf16(a, bi, aI[nt], 0, 0, 0);
            aJ[nt] = __builtin_amdgcn_mfma_f32_16x16x32_bf16(a, bj, aJ[nt], 0, 0, 0);
        }
    }
    unsigned short* partih = (unsigned short*)ws + (size_t)OFF_PARTIH * 2;
    unsigned short* partjh = (unsigned short*)ws + (size_t)OFF_PARTJH * 2;
#pragma unroll
    for (int nt = 0; nt < 4; nt++) {
        int col = w * 64 + nt * 16 + (ln & 15);
        float e1 = eb1[l * 256 + col];
#pragma unroll
        for (int r = 0; r < 4; r++) {
            int n = n0 + 4 * (ln >> 4) + r;
            int gb = n / 24;
            float vi = aI[nt][r] + e1 + ws[OFF_LATW + (size_t)(l * 128 + gb) * 256 + col];
            partih[(size_t)n * 256 + col] = f2bf(vi);
            partjh[(size_t)n * 256 + col] = f2bf(aJ[nt][r]);
        }
    }
}

// ---------------- fused edge pipeline (swizzled LDS, in-register aggregation) ----------------
// grid 1536: b = bid&127 (12 blocks of a graph share an XCD L2), c = bid>>7, i0 = 2c
__global__ void __launch_bounds__(256, 4) k_edge(int l, const float* frac, const float* eb2, float* ws) {
    __shared__ __align__(16) unsigned short s_u[48 * 256];   // ef1 (swizzled); demb aliased in first 6 KB
    __shared__ __align__(16) unsigned short s_pJ[24][264];
    __shared__ __align__(16) unsigned short s_pI[2][264];
    __shared__ float s_fc[24][3];
    int tid = threadIdx.x, w = tid >> 6, ln = tid & 63;
    int l15 = ln & 15, g = ln >> 4;
    int b = blockIdx.x & 127, c = blockIdx.x >> 7;
    int i0 = c * 2;

    const unsigned short* partjh = (const unsigned short*)ws + (size_t)OFF_PARTJH * 2 + (size_t)b * 24 * 256;
    const unsigned short* partih = (const unsigned short*)ws + (size_t)OFF_PARTIH * 2 + (size_t)(b * 24 + i0) * 256;
    for (int idx = tid; idx < 72; idx += 256) s_fc[idx / 3][idx % 3] = frac[b * 72 + idx];
    for (int idx = tid; idx < 768; idx += 256) {
        int row = idx >> 5, c8 = idx & 31;
        *(uint4*)&s_pJ[row][c8 * 8] = *(const uint4*)&partjh[row * 256 + c8 * 8];
    }
    if (tid < 64) {
        int row = tid >> 5, c8 = tid & 31;
        *(uint4*)&s_pI[row][c8 * 8] = *(const uint4*)&partih[row * 256 + c8 * 8];
    }
    __syncthreads();
    // demb [48][64] bf16, swizzled chunk ^= row&7; k 60..63 zeroed
    for (int idx = tid; idx < 3072; idx += 256) {
        int row = idx >> 6, k = idx & 63;
        unsigned short v = 0;
        if (k < 60) {
            int kk = (k < 30) ? k : k - 30;
            int d = kk / 10, f = kk % 10;
            int hi = (row >= 24);
            int j = row - (hi ? 24 : 0);
            float fd = s_fc[j][d] - s_fc[i0 + hi][d];
            fd -= floorf(fd);
            float ang = fd * (6.283185307179586f * (float)f);
            v = f2bf((k < 30) ? __sinf(ang) : __cosf(ang));
        }
        s_u[(row << 6) + (((k >> 3) ^ (row & 7)) << 3) + (k & 7)] = v;
    }
    __syncthreads();

    const unsigned short* wsu = (const unsigned short*)ws;
    // GEMM1: [48 x 64] @ [64 x 256]
    const unsigned short* pw1d = wsu + (size_t)OFF_PW1D * 2 + (size_t)l * 16384;
    f32x4 acc[3][4] = {};
    for (int ks = 0; ks < 2; ks++) {
        bf16x8 a[3];
        int kb = ks * 4 + g;
#pragma unroll
        for (int mt = 0; mt < 3; mt++) {
            int row = mt * 16 + l15;
            a[mt] = *(const bf16x8*)&s_u[(row << 6) + ((kb ^ (row & 7)) << 3)];
        }
#pragma unroll
        for (int nt = 0; nt < 4; nt++) {
            bf16x8 bf = *(const bf16x8*)&pw1d[((size_t)(ks * 16 + w * 4 + nt) * 64 + ln) * 8];
#pragma unroll
            for (int mt = 0; mt < 3; mt++)
                acc[mt][nt] = __builtin_amdgcn_mfma_f32_16x16x32_bf16(a[mt], bf, acc[mt][nt], 0, 0, 0);
        }
    }
    __syncthreads();   // all demb reads done; ef1 may now overwrite the aliased region
    float pIv[2][4];
#pragma unroll
    for (int hi = 0; hi < 2; hi++)
#pragma unroll
        for (int nt = 0; nt < 4; nt++) pIv[hi][nt] = bf2f(s_pI[hi][w * 64 + nt * 16 + l15]);
#pragma unroll
    for (int mt = 0; mt < 3; mt++)
#pragma unroll
        for (int nt = 0; nt < 4; nt++) {
            int col = w * 64 + nt * 16 + l15;
#pragma unroll
            for (int r = 0; r < 4; r++) {
                int row = mt * 16 + 4 * g + r;
                int hi = (row >= 24);
                int j = row - 24 * hi;
                float v = acc[mt][nt][r] + pIv[hi][nt] + bf2f(s_pJ[j][col]);
                s_u[(row << 8) + ((((col >> 3) ^ (row & 7))) << 3) + (col & 7)] = f2bf(silu_f(v));
            }
        }
    __syncthreads();
    // GEMM2: [48 x 256] @ [256 x 256]
    const unsigned short* pw2 = wsu + (size_t)OFF_PW2 * 2 + (size_t)l * 65536;
    f32x4 acc2[3][4] = {};
    for (int ks = 0; ks < 8; ks++) {
        bf16x8 a[3];
        int kb = ks * 4 + g;
#pragma unroll
        for (int mt = 0; mt < 3; mt++) {
            int row = mt * 16 + l15;
            a[mt] = *(const bf16x8*)&s_u[(row << 8) + ((kb ^ (row & 7)) << 3)];
        }
#pragma unroll
        for (int nt = 0; nt < 4; nt++) {
            bf16x8 bf = *(const bf16x8*)&pw2[((size_t)(ks * 16 + w * 4 + nt) * 64 + ln) * 8];
#pragma unroll
            for (int mt = 0; mt < 3; mt++)
                acc2[mt][nt] = __builtin_amdgcn_mfma_f32_16x16x32_bf16(a[mt], bf, acc2[mt][nt], 0, 0, 0);
        }
    }
    // in-register silu + aggregation over 24 edges per i-group
    float s0[4] = {}, s1[4] = {};
#pragma unroll
    for (int nt = 0; nt < 4; nt++) {
        int col = w * 64 + nt * 16 + l15;
        float b2 = eb2[l * 256 + col];
        // mt=0: rows 0..15 -> hi0 ; mt=2: rows 32..47 -> hi1 ; mt=1: g<2 -> hi0 else hi1
#pragma unroll
        for (int r = 0; r < 4; r++) s0[nt] += silu_f(acc2[0][nt][r] + b2);
        float m = 0.f;
#pragma unroll
        for (int r = 0; r < 4; r++) m += silu_f(acc2[1][nt][r] + b2);
        if (g < 2) s0[nt] += m; else s1[nt] += m;
#pragma unroll
        for (int r = 0; r < 4; r++) s1[nt] += silu_f(acc2[2][nt][r] + b2);
    }
#pragma unroll
    for (int nt = 0; nt < 4; nt++) {
        s0[nt] += __shfl_xor(s0[nt], 16);
        s0[nt] += __shfl_xor(s0[nt], 32);
        s1[nt] += __shfl_xor(s1[nt], 16);
        s1[nt] += __shfl_xor(s1[nt], 32);
    }
    unsigned short* aggh = (unsigned short*)ws + (size_t)OFF_AGGH * 2;
    if (g == 0) {
#pragma unroll
        for (int nt = 0; nt < 4; nt++) {
            int col = w * 64 + nt * 16 + l15;
            aggh[(size_t)(b * 24 + i0) * 256 + col]     = f2bf(s0[nt] * (1.0f / 24.0f));
            aggh[(size_t)(b * 24 + i0 + 1) * 256 + col] = f2bf(s1[nt] * (1.0f / 24.0f));
        }
    }
}

// ---------------- node MLP + residual (MFMA), 16 nodes/block ----------------
__global__ void __launch_bounds__(256) k_node(int l, const float* nb1, const float* nb2, float* ws) {
    __shared__ __align__(16) unsigned short s_a[16][536];
    __shared__ __align__(16) unsigned short s_h[16][264];
    int tid = threadIdx.x, w = tid >> 6, ln = tid & 63;
    int n0 = blockIdx.x * 16;
    const unsigned short* nfmidh = (const unsigned short*)ws + (size_t)OFF_NFMIDH * 2;
    const unsigned short* aggh   = (const unsigned short*)ws + (size_t)OFF_AGGH * 2;
#pragma unroll
    for (int t = 0; t < 2; t++) {
        int idx = tid + t * 256;
        int row = idx >> 5, c8 = idx & 31;
        *(uint4*)&s_a[row][c8 * 8]       = *(const uint4*)&nfmidh[(size_t)(n0 + row) * 256 + c8 * 8];
        *(uint4*)&s_a[row][256 + c8 * 8] = *(const uint4*)&aggh[(size_t)(n0 + row) * 256 + c8 * 8];
    }
    __syncthreads();
    const unsigned short* wsu = (const unsigned short*)ws;
    // GEMM1: [16 x 512] @ [512 x 256]
    const unsigned short* p1 = wsu + (size_t)OFF_PNW1 * 2 + (size_t)l * 131072;
    f32x4 acc[4] = {};
    for (int ks = 0; ks < 16; ks++) {
        bf16x8 a = *(const bf16x8*)&s_a[ln & 15][ks * 32 + (ln >> 4) * 8];
#pragma unroll
        for (int nt = 0; nt < 4; nt++) {
            bf16x8 bf = *(const bf16x8*)&p1[((size_t)(ks * 16 + w * 4 + nt) * 64 + ln) * 8];
            acc[nt] = __builtin_amdgcn_mfma_f32_16x16x32_bf16(a, bf, acc[nt], 0, 0, 0);
        }
    }
#pragma unroll
    for (int nt = 0; nt < 4; nt++) {
        int col = w * 64 + nt * 16 + (ln & 15);
        float b1 = nb1[l * 256 + col];
#pragma unroll
        for (int r = 0; r < 4; r++) s_h[4 * (ln >> 4) + r][col] = f2bf(silu_f(acc[nt][r] + b1));
    }
    __syncthreads();
    // GEMM2: [16 x 256] @ [256 x 256]
    const unsigned short* p2 = wsu + (size_t)OFF_PNW2 * 2 + (size_t)l * 65536;
    f32x4 a2[4] = {};
    for (int ks = 0; ks < 8; ks++) {
        bf16x8 a = *(const bf16x8*)&s_h[ln & 15][ks * 32 + (ln >> 4) * 8];
#pragma unroll
        for (int nt = 0; nt < 4; nt++) {
            bf16x8 bf = *(const bf16x8*)&p2[((size_t)(ks * 16 + w * 4 + nt) * 64 + ln) * 8];
            a2[nt] = __builtin_amdgcn_mfma_f32_16x16x32_bf16(a, bf, a2[nt], 0, 0, 0);
        }
    }
    unsigned short* nfh = (unsigned short*)ws + (size_t)OFF_NFH * 2;
#pragma unroll
    for (int nt = 0; nt < 4; nt++) {
        int col = w * 64 + nt * 16 + (ln & 15);
        float b2 = nb2[l * 256 + col];
#pragma unroll
        for (int r = 0; r < 4; r++) {
            int n = n0 + 4 * (ln >> 4) + r;
            float v = bf2f(nfmidh[(size_t)n * 256 + col]) + silu_f(a2[nt][r] + b2);
            ws[OFF_NF + (size_t)n * 256 + col] = v;
            nfh[(size_t)n * 256 + col] = f2bf(v);
        }
    }
}

// ---------------- outputs: atom_types_out, coords_out, nf copy ----------------
__global__ void k_out_node(const float* b_type, const float* w_coord, const float* ws, float* out) {
    __shared__ float nf8[8 * 256];
    int n0 = blockIdx.x * 8, tid = threadIdx.x;
    for (int idx = tid; idx < 2048; idx += 256) nf8[idx] = ws[OFF_NF + (size_t)n0 * 256 + idx];
    __syncthreads();
    for (int idx = tid; idx < 2048; idx += 256) out[OUT_NF + (size_t)n0 * 256 + idx] = nf8[idx];
    const float* WT = ws + OFF_WTYPET;  // [256][103]
    for (int idx = tid; idx < 8 * 103; idx += 256) {
        int p = idx / 103, a = idx % 103;
        float a0 = b_type[a], a1 = 0.f, a2 = 0.f, a3 = 0.f;
        for (int k = 0; k < 256; k += 4) {
            a0 += nf8[p * 256 + k]     * WT[k * 103 + a];
            a1 += nf8[p * 256 + k + 1] * WT[(k + 1) * 103 + a];
            a2 += nf8[p * 256 + k + 2] * WT[(k + 2) * 103 + a];
            a3 += nf8[p * 256 + k + 3] * WT[(k + 3) * 103 + a];
        }
        out[OUT_TYPES + (size_t)(n0 + p) * 103 + a] = a0 + a1 + a2 + a3;
    }
    if (tid < 24) {
        int p = tid / 3, c = tid % 3;
        float a0 = 0.f;
        for (int k = 0; k < 256; k++) a0 += nf8[p * 256 + k] * w_coord[c * 256 + k];
        out[OUT_COORD + (size_t)(n0 + p) * 3 + c] = a0;
    }
}

// ---------------- lattice_out ----------------
__global__ void k_out_graph(const float* lattices, const float* w_latt, const float* ws, float* out) {
    __shared__ float gf[256];
    __shared__ float lo[9];
    int b = blockIdx.x, h = threadIdx.x;
    float g = 0.f;
#pragma unroll
    for (int i = 0; i < 24; i++) g += ws[OFF_NF + (size_t)(b * 24 + i) * 256 + h];
    gf[h] = g * (1.0f / 24.0f);
    __syncthreads();
    if (h < 9) {
        float a0 = 0.f;
        for (int k = 0; k < 256; k++) a0 += gf[k] * w_latt[h * 256 + k];
        lo[h] = a0;
    }
    __syncthreads();
    if (h < 9) {
        int i = h / 3, kk = h % 3;
        float a0 = 0.f;
#pragma unroll
        for (int j = 0; j < 3; j++) a0 += lo[i * 3 + j] * lattices[b * 9 + j * 3 + kk];
        out[OUT_LATT + b * 9 + h] = a0;
    }
}

extern "C" void kernel_launch(void* const* d_in, const int* in_sizes, int n_in,
                              void* d_out, int out_size, void* d_ws, size_t ws_size,
                              hipStream_t stream) {
    const float* atom_types = (const float*)d_in[0];
    const float* frac       = (const float*)d_in[1];
    const float* lattices   = (const float*)d_in[2];
    const float* t_in       = (const float*)d_in[3];
    const float* text       = (const float*)d_in[4];
    const float* w_emb      = (const float*)d_in[5];
    const float* b_emb      = (const float*)d_in[6];
    const float* w_cond     = (const float*)d_in[7];
    const float* b_cond     = (const float*)d_in[8];
    const float* w_proj     = (const float*)d_in[9];
    const float* b_proj     = (const float*)d_in[10];
    const float* film_g     = (const float*)d_in[11];
    const float* film_b     = (const float*)d_in[12];
    const float* ew1        = (const float*)d_in[13];
    const float* eb1        = (const float*)d_in[14];
    const float* ew2        = (const float*)d_in[15];
    const float* eb2        = (const float*)d_in[16];
    const float* nw1        = (const float*)d_in[17];
    const float* nb1        = (const float*)d_in[18];
    const float* nw2        = (const float*)d_in[19];
    const float* nb2        = (const float*)d_in[20];
    const float* w_coord    = (const float*)d_in[21];
    const float* w_latt     = (const float*)d_in[22];
    const float* w_type     = (const float*)d_in[23];
    const float* b_type     = (const float*)d_in[24];
    float* ws  = (float*)d_ws;
    float* out = (float*)d_out;

    k_prep<<<7666, 256, 0, stream>>>(w_emb, w_cond, w_proj, ew1, ew2, nw1, nw2, w_type, ws);
    k_latips<<<5, 256, 0, stream>>>(lattices, ws);
    k_latw<<<B_, 256, 0, stream>>>(ws);
    k_cond<<<B_, 256, 0, stream>>>(t_in, text, b_cond, ws);
    k_embed<<<N_ / 8, 256, 0, stream>>>(atom_types, b_emb, ws);
    for (int l = 0; l < NLAYERS; l++) {
        k_film<<<N_ / 16, 256, 0, stream>>>(l, b_proj, film_g, film_b, eb1, ws);
        k_edge<<<N_ * 12 / 24, 256, 0, stream>>>(l, frac, eb2, ws);
        k_node<<<N_ / 16, 256, 0, stream>>>(l, nb1, nb2, ws);
    }
    k_out_node<<<N_ / 8, 256, 0, stream>>>(b_type, w_coord, ws, out);
    k_out_graph<<<B_, 256, 0, stream>>>(lattices, w_latt, ws, out);
}

// Round 7
// 375.960 us; speedup vs baseline: 6.9031x; 1.0857x over previous
//
#include <hip/hip_runtime.h>
#include <math.h>

// ---- problem constants ----
#define B_      128
#define A_      24
#define N_      3072     // B_*A_
#define NLAYERS 4

// ---- workspace layout (float-element offsets) ----
// NOTE: each [3072][256] bf16 buffer = 786432 ushorts = 393216 float slots.
#define OFF_COND    0         // [128][512] f32                      (65536)
#define OFF_LATW    65536     // [4][128][256] f32                   (131072)
#define OFF_NFMIDH  196608    // [3072][256] bf16                    (393216)
#define OFF_AGGH    589824    // [3072][256] bf16                    (393216)
#define OFF_PARTIH  983040    // [3072][256] bf16 (incl. eb1+latW)   (393216)
#define OFF_PARTJH  1376256   // [3072][256] bf16                    (393216)
#define OFF_W1LATT  1769472   // [4][9][256] f32                     (9216)
#define OFF_PW1A    1778688   // [4][8][16][64][8] bf16              (131072)
#define OFF_PW1B    1909760   //                                     (131072)
#define OFF_PW1D    2040832   // [4][2][16][64][8] bf16              (32768)
#define OFF_PW2     2073600   // [4][8][16][64][8] bf16              (131072)
#define OFF_PWPROJ  2204672   // [8][16][64][8] bf16                 (32768)
#define OFF_PNW1    2237440   // [4][16][16][64][8] bf16             (262144)
#define OFF_PNW2    2499584   // [4][8][16][64][8] bf16              (131072)
#define OFF_PWEMB   2630656   // [4 ks][16 nt][64][8] bf16 (K pad)   (16384)
#define OFF_PWCOND  2647040   // [12 ks][32 nt][64][8] bf16 (K=384)  (98304)
#define OFF_PWTYPE  2745344   // [8 ks][7 nt][64][8] bf16 (N pad)    (14336)
// end 2759680 floats ~ 10.5 MiB

// output offsets (floats): types | lattice | coords | nf
#define OUT_TYPES  0
#define OUT_LATT   316416
#define OUT_COORD  317568
#define OUT_NF     326784

typedef __attribute__((ext_vector_type(8))) short bf16x8;
typedef __attribute__((ext_vector_type(4))) float f32x4;

__device__ __forceinline__ float silu_f(float x) { return x / (1.0f + __expf(-x)); }
__device__ __forceinline__ unsigned short f2bf(float x) {
    unsigned int u = __float_as_uint(x);
    return (unsigned short)((u + 0x7FFFu + ((u >> 16) & 1u)) >> 16);
}
__device__ __forceinline__ float bf2f(unsigned short h) {
    return __uint_as_float(((unsigned int)h) << 16);
}

// ---------------- weight packs ----------------
// generic pack: pack[((ks*NT + nt)*64 + lane)*8 + j] = W[k][n],
//   k = ks*32 + (lane>>4)*8 + j,  n = nt*16 + (lane&15)
__global__ void k_prep(const float* w_emb, const float* w_cond, const float* w_proj,
                       const float* ew1, const float* ew2, const float* nw1, const float* nw2,
                       const float* w_type, float* ws) {
    int idx = blockIdx.x * blockDim.x + threadIdx.x;
    unsigned short* pu = (unsigned short*)ws;
    int i = idx;
    if (i < 9216)   { int l = i / 2304, r = (i % 2304) / 256, h = i % 256;
                      ws[OFF_W1LATT + i] = ew1[((size_t)l * 256 + h) * 581 + 512 + r]; return; }        i -= 9216;
    if (i < 262144) { int l = i >> 16, r = i & 65535, ks = r >> 13, r2 = r & 8191,
                      nt = r2 >> 9, r3 = r2 & 511, lane = r3 >> 3, j = r3 & 7;
                      int k = ks * 32 + (lane >> 4) * 8 + j, n = nt * 16 + (lane & 15);
                      pu[(size_t)OFF_PW1A * 2 + i] = f2bf(ew1[((size_t)l * 256 + n) * 581 + k]); return; } i -= 262144;
    if (i < 262144) { int l = i >> 16, r = i & 65535, ks = r >> 13, r2 = r & 8191,
                      nt = r2 >> 9, r3 = r2 & 511, lane = r3 >> 3, j = r3 & 7;
                      int k = ks * 32 + (lane >> 4) * 8 + j, n = nt * 16 + (lane & 15);
                      pu[(size_t)OFF_PW1B * 2 + i] = f2bf(ew1[((size_t)l * 256 + n) * 581 + 256 + k]); return; } i -= 262144;
    if (i < 65536)  { int l = i >> 14, r = i & 16383, ks = r >> 13, r2 = r & 8191,
                      nt = r2 >> 9, r3 = r2 & 511, lane = r3 >> 3, j = r3 & 7;
                      int kp = ks * 32 + (lane >> 4) * 8 + j, n = nt * 16 + (lane & 15);
                      float v = (kp < 60) ? ew1[((size_t)l * 256 + n) * 581 + 521 + kp] : 0.0f;
                      pu[(size_t)OFF_PW1D * 2 + i] = f2bf(v); return; }                                  i -= 65536;
    if (i < 262144) { int l = i >> 16, r = i & 65535, ks = r >> 13, r2 = r & 8191,
                      nt = r2 >> 9, r3 = r2 & 511, lane = r3 >> 3, j = r3 & 7;
                      int k = ks * 32 + (lane >> 4) * 8 + j, n = nt * 16 + (lane & 15);
                      pu[(size_t)OFF_PW2 * 2 + i] = f2bf(ew2[((size_t)l * 256 + n) * 256 + k]); return; } i -= 262144;
    if (i < 65536)  { int ks = i >> 13, r2 = i & 8191,
                      nt = r2 >> 9, r3 = r2 & 511, lane = r3 >> 3, j = r3 & 7;
                      int k = ks * 32 + (lane >> 4) * 8 + j, n = nt * 16 + (lane & 15);
                      pu[(size_t)OFF_PWPROJ * 2 + i] = f2bf(w_proj[(size_t)n * 256 + k]); return; }      i -= 65536;
    if (i < 524288) { int l = i >> 17, r = i & 131071, ks = r >> 13, r2 = r & 8191,
                      nt = r2 >> 9, r3 = r2 & 511, lane = r3 >> 3, j = r3 & 7;
                      int k = ks * 32 + (lane >> 4) * 8 + j, n = nt * 16 + (lane & 15);
                      pu[(size_t)OFF_PNW1 * 2 + i] = f2bf(nw1[((size_t)l * 256 + n) * 512 + k]); return; } i -= 524288;
    if (i < 262144) { int l = i >> 16, r = i & 65535, ks = r >> 13, r2 = r & 8191,
                      nt = r2 >> 9, r3 = r2 & 511, lane = r3 >> 3, j = r3 & 7;
                      int k = ks * 32 + (lane >> 4) * 8 + j, n = nt * 16 + (lane & 15);
                      pu[(size_t)OFF_PNW2 * 2 + i] = f2bf(nw2[((size_t)l * 256 + n) * 256 + k]); return; } i -= 262144;
    if (i < 32768)  { int ks = i >> 13, r2 = i & 8191,
                      nt = r2 >> 9, r3 = r2 & 511, lane = r3 >> 3, j = r3 & 7;
                      int k = ks * 32 + (lane >> 4) * 8 + j, n = nt * 16 + (lane & 15);
                      float v = (k < 103) ? w_emb[(size_t)n * 103 + k] : 0.0f;
                      pu[(size_t)OFF_PWEMB * 2 + i] = f2bf(v); return; }                                 i -= 32768;
    if (i < 196608) { int ks = i / 16384, r2 = i & 16383,
                      nt = r2 >> 9, r3 = r2 & 511, lane = r3 >> 3, j = r3 & 7;
                      int k = ks * 32 + (lane >> 4) * 8 + j, n = nt * 16 + (lane & 15);
                      pu[(size_t)OFF_PWCOND * 2 + i] = f2bf(w_cond[(size_t)n * 384 + k]); return; }      i -= 196608;
    { int ks = i / 3584, r2 = i % 3584,
      nt = r2 >> 9, r3 = r2 & 511, lane = r3 >> 3, j = r3 & 7;
      int k = ks * 32 + (lane >> 4) * 8 + j, a = nt * 16 + (lane & 15);
      float v = (a < 103) ? w_type[(size_t)a * 256 + k] : 0.0f;
      pu[(size_t)OFF_PWTYPE * 2 + i] = f2bf(v); }
}

// ---------------- setup: latips + latW + cond (MFMA), 8 blocks x 16 graphs ----------------
__global__ void __launch_bounds__(256) k_setup(const float* lat, const float* t_in, const float* tx,
                                               const float* b_cond, float* ws) {
    __shared__ __align__(16) unsigned short s_ct[16][392];
    __shared__ float s_lat[16][9];
    int tid = threadIdx.x, w = tid >> 6, ln = tid & 63;
    int l15 = ln & 15, g = ln >> 4;
    int g0 = blockIdx.x * 16;
    // latips
    if (tid < 144) {
        int gl = tid / 9, r = tid % 9, ii = r / 3, kk = r % 3;
        const float* L = lat + (g0 + gl) * 9;
        s_lat[gl][r] = L[ii*3+0]*L[kk*3+0] + L[ii*3+1]*L[kk*3+1] + L[ii*3+2]*L[kk*3+2];
    }
    // cond A-tile: [16][384] = [t | text] bf16
    for (int idx = tid; idx < 16 * 384; idx += 256) {
        int row = idx / 384, k = idx % 384;
        float v = (k < 256) ? t_in[(size_t)(g0 + row) * 256 + k] : tx[(size_t)(g0 + row) * 128 + (k - 256)];
        s_ct[row][k] = f2bf(v);
    }
    __syncthreads();
    // latW
    for (int idx = tid; idx < 16384; idx += 256) {
        int l = idx >> 12, gl = (idx >> 8) & 15, h = idx & 255;
        float a = 0.f;
#pragma unroll
        for (int r = 0; r < 9; r++) a += s_lat[gl][r] * ws[OFF_W1LATT + (l * 9 + r) * 256 + h];
        ws[OFF_LATW + (size_t)(l * 128 + g0 + gl) * 256 + h] = a;
    }
    // cond GEMM: [16 x 384] @ [384 x 512]
    const unsigned short* pc = (const unsigned short*)ws + (size_t)OFF_PWCOND * 2;
    f32x4 acc[8] = {};
    for (int ks = 0; ks < 12; ks++) {
        bf16x8 a = *(const bf16x8*)&s_ct[l15][ks * 32 + g * 8];
#pragma unroll
        for (int q = 0; q < 8; q++) {
            int nt = w * 8 + q;
            bf16x8 bf = *(const bf16x8*)&pc[((size_t)(ks * 32 + nt) * 64 + ln) * 8];
            acc[q] = __builtin_amdgcn_mfma_f32_16x16x32_bf16(a, bf, acc[q], 0, 0, 0);
        }
    }
#pragma unroll
    for (int q = 0; q < 8; q++) {
        int col = w * 128 + q * 16 + l15;
        float bc = b_cond[col];
#pragma unroll
        for (int r = 0; r < 4; r++) {
            int gg = g0 + 4 * g + r;
            ws[OFF_COND + (size_t)gg * 512 + col] = silu_f(acc[q][r] + bc);
        }
    }
}

// ---------------- fused node-MLP(l-1) [or embed] + FiLM(l) + PartI/PartJ(l), 16 nodes/block ----------------
__global__ void __launch_bounds__(256) k_fnf(int l, const float* at, const float* b_emb,
                                             const float* nb1, const float* nb2,
                                             const float* b_proj, const float* film_g, const float* film_b,
                                             const float* eb1, float* ws) {
    __shared__ __align__(16) unsigned short s_in[16][536];
    __shared__ __align__(16) unsigned short s_h[16][264];
    __shared__ __align__(16) unsigned short s_a[16][264];
    __shared__ float s_nf[16][260];
    __shared__ float s_mu[16], s_rs[16];
    float (*s_c)[268] = (float(*)[268])&s_in[0][0];   // aliased over s_in (used after node phase)
    int tid = threadIdx.x, w = tid >> 6, ln = tid & 63;
    int l15 = ln & 15, g = ln >> 4;
    int n0 = blockIdx.x * 16;
    const unsigned short* wsu = (const unsigned short*)ws;
    unsigned short* wsw = (unsigned short*)ws;

    f32x4 accn[4] = {};
    if (l == 0) {
        // ---- embed: nf = at @ w_emb^T + b_emb ----
        for (int idx = tid; idx < 16 * 128; idx += 256) {
            int row = idx >> 7, k = idx & 127;
            s_in[row][k] = (k < 103) ? f2bf(at[(size_t)(n0 + row) * 103 + k]) : (unsigned short)0;
        }
        __syncthreads();
        const unsigned short* pe = wsu + (size_t)OFF_PWEMB * 2;
        for (int ks = 0; ks < 4; ks++) {
            bf16x8 a = *(const bf16x8*)&s_in[l15][ks * 32 + g * 8];
#pragma unroll
            for (int nt = 0; nt < 4; nt++) {
                bf16x8 bf = *(const bf16x8*)&pe[((size_t)(ks * 16 + w * 4 + nt) * 64 + ln) * 8];
                accn[nt] = __builtin_amdgcn_mfma_f32_16x16x32_bf16(a, bf, accn[nt], 0, 0, 0);
            }
        }
#pragma unroll
        for (int nt = 0; nt < 4; nt++) {
            int col = w * 64 + nt * 16 + l15;
            float be = b_emb[col];
#pragma unroll
            for (int r = 0; r < 4; r++) {
                int row = 4 * g + r;
                float v = accn[nt][r] + be;
                s_nf[row][col] = v;
                s_a[row][col] = f2bf(v);
            }
        }
    } else {
        // ---- node MLP of layer l-1 ----
        int lp = l - 1;
        const unsigned short* nfmidh = wsu + (size_t)OFF_NFMIDH * 2;
        const unsigned short* aggh   = wsu + (size_t)OFF_AGGH * 2;
#pragma unroll
        for (int t = 0; t < 2; t++) {
            int idx = tid + t * 256;
            int row = idx >> 5, c8 = idx & 31;
            *(uint4*)&s_in[row][c8 * 8]       = *(const uint4*)&nfmidh[(size_t)(n0 + row) * 256 + c8 * 8];
            *(uint4*)&s_in[row][256 + c8 * 8] = *(const uint4*)&aggh[(size_t)(n0 + row) * 256 + c8 * 8];
        }
        __syncthreads();
        const unsigned short* p1 = wsu + (size_t)OFF_PNW1 * 2 + (size_t)lp * 131072;
        f32x4 acc[4] = {};
        for (int ks = 0; ks < 16; ks++) {
            bf16x8 a = *(const bf16x8*)&s_in[l15][ks * 32 + g * 8];
#pragma unroll
            for (int nt = 0; nt < 4; nt++) {
                bf16x8 bf = *(const bf16x8*)&p1[((size_t)(ks * 16 + w * 4 + nt) * 64 + ln) * 8];
                acc[nt] = __builtin_amdgcn_mfma_f32_16x16x32_bf16(a, bf, acc[nt], 0, 0, 0);
            }
        }
#pragma unroll
        for (int nt = 0; nt < 4; nt++) {
            int col = w * 64 + nt * 16 + l15;
            float b1 = nb1[lp * 256 + col];
#pragma unroll
            for (int r = 0; r < 4; r++) s_h[4 * g + r][col] = f2bf(silu_f(acc[nt][r] + b1));
        }
        __syncthreads();
        const unsigned short* p2 = wsu + (size_t)OFF_PNW2 * 2 + (size_t)lp * 65536;
        for (int ks = 0; ks < 8; ks++) {
            bf16x8 a = *(const bf16x8*)&s_h[l15][ks * 32 + g * 8];
#pragma unroll
            for (int nt = 0; nt < 4; nt++) {
                bf16x8 bf = *(const bf16x8*)&p2[((size_t)(ks * 16 + w * 4 + nt) * 64 + ln) * 8];
                accn[nt] = __builtin_amdgcn_mfma_f32_16x16x32_bf16(a, bf, accn[nt], 0, 0, 0);
            }
        }
#pragma unroll
        for (int nt = 0; nt < 4; nt++) {
            int col = w * 64 + nt * 16 + l15;
            float b2 = nb2[lp * 256 + col];
#pragma unroll
            for (int r = 0; r < 4; r++) {
                int row = 4 * g + r;
                float v = bf2f(s_in[row][col]) + silu_f(accn[nt][r] + b2);
                s_nf[row][col] = v;
                s_a[row][col] = f2bf(v);
            }
        }
    }
    __syncthreads();
    // ---- proj GEMM: [16 x 256] @ [256 x 256] ----
    const unsigned short* pwp = wsu + (size_t)OFF_PWPROJ * 2;
    f32x4 accp[4] = {};
    for (int ks = 0; ks < 8; ks++) {
        bf16x8 a = *(const bf16x8*)&s_a[l15][ks * 32 + g * 8];
#pragma unroll
        for (int nt = 0; nt < 4; nt++) {
            bf16x8 bf = *(const bf16x8*)&pwp[((size_t)(ks * 16 + w * 4 + nt) * 64 + ln) * 8];
            accp[nt] = __builtin_amdgcn_mfma_f32_16x16x32_bf16(a, bf, accp[nt], 0, 0, 0);
        }
    }
#pragma unroll
    for (int nt = 0; nt < 4; nt++) {
        int col = w * 64 + nt * 16 + l15;
        float bp = b_proj[col];
#pragma unroll
        for (int r = 0; r < 4; r++) s_c[4 * g + r][col] = accp[nt][r] + bp;
    }
    __syncthreads();
    // ---- LN stats: wave w handles rows 4w..4w+3 ----
    for (int r4 = 0; r4 < 4; r4++) {
        int row = w * 4 + r4;
        float s = 0.f, q = 0.f;
        for (int c = ln; c < 256; c += 64) { float v = s_c[row][c]; s += v; q += v * v; }
#pragma unroll
        for (int o = 1; o < 64; o <<= 1) { s += __shfl_xor(s, o); q += __shfl_xor(q, o); }
        if (ln == 0) {
            float mu = s * (1.0f / 256.0f);
            float var = q * (1.0f / 256.0f) - mu * mu;
            s_mu[row] = mu; s_rs[row] = rsqrtf(var + 1e-5f);
        }
    }
    __syncthreads();
    // ---- FiLM epilogue (per-column thread) ----
    {
        float gg = film_g[tid], bb = film_b[tid];
        unsigned short* nfmidh = wsw + (size_t)OFF_NFMIDH * 2;
        for (int row = 0; row < 16; row++) {
            int n = n0 + row, b = n / 24;
            float sc = ws[OFF_COND + (size_t)b * 512 + tid];
            float sh = ws[OFF_COND + (size_t)b * 512 + 256 + tid];
            float yn = (s_c[row][tid] - s_mu[row]) * s_rs[row] * gg + bb;
            float outv = s_nf[row][tid] + silu_f(yn * sc + sh);
            unsigned short ob = f2bf(outv);
            nfmidh[(size_t)n * 256 + tid] = ob;
            s_a[row][tid] = ob;
        }
    }
    __syncthreads();
    // ---- PartI/PartJ GEMMs ----
    const unsigned short* pA = wsu + (size_t)OFF_PW1A * 2 + (size_t)l * 65536;
    const unsigned short* pB = wsu + (size_t)OFF_PW1B * 2 + (size_t)l * 65536;
    f32x4 aI[4] = {}, aJ[4] = {};
    for (int ks = 0; ks < 8; ks++) {
        bf16x8 a = *(const bf16x8*)&s_a[l15][ks * 32 + g * 8];
#pragma unroll
        for (int nt = 0; nt < 4; nt++) {
            bf16x8 bi = *(const bf16x8*)&pA[((size_t)(ks * 16 + w * 4 + nt) * 64 + ln) * 8];
            bf16x8 bj = *(const bf16x8*)&pB[((size_t)(ks * 16 + w * 4 + nt) * 64 + ln) * 8];
            aI[nt] = __builtin_amdgcn_mfma_f32_16x16x32_bf16(a, bi, aI[nt], 0, 0, 0);
            aJ[nt] = __builtin_amdgcn_mfma_f32_16x16x32_bf16(a, bj, aJ[nt], 0, 0, 0);
        }
    }
    unsigned short* partih = wsw + (size_t)OFF_PARTIH * 2;
    unsigned short* partjh = wsw + (size_t)OFF_PARTJH * 2;
#pragma unroll
    for (int nt = 0; nt < 4; nt++) {
        int col = w * 64 + nt * 16 + l15;
        float e1 = eb1[l * 256 + col];
#pragma unroll
        for (int r = 0; r < 4; r++) {
            int n = n0 + 4 * g + r;
            int gb = n / 24;
            float vi = aI[nt][r] + e1 + ws[OFF_LATW + (size_t)(l * 128 + gb) * 256 + col];
            partih[(size_t)n * 256 + col] = f2bf(vi);
            partjh[(size_t)n * 256 + col] = f2bf(aJ[nt][r]);
        }
    }
}

// ---------------- fused edge pipeline (swizzled LDS, in-register aggregation) ----------------
__global__ void __launch_bounds__(256, 4) k_edge(int l, const float* frac, const float* eb2, float* ws) {
    __shared__ __align__(16) unsigned short s_u[48 * 256];   // ef1 (swizzled); demb aliased in first 6 KB
    __shared__ __align__(16) unsigned short s_pJ[24][264];
    __shared__ __align__(16) unsigned short s_pI[2][264];
    __shared__ float s_fc[24][3];
    int tid = threadIdx.x, w = tid >> 6, ln = tid & 63;
    int l15 = ln & 15, g = ln >> 4;
    int b = blockIdx.x & 127, c = blockIdx.x >> 7;
    int i0 = c * 2;

    const unsigned short* partjh = (const unsigned short*)ws + (size_t)OFF_PARTJH * 2 + (size_t)b * 24 * 256;
    const unsigned short* partih = (const unsigned short*)ws + (size_t)OFF_PARTIH * 2 + (size_t)(b * 24 + i0) * 256;
    for (int idx = tid; idx < 72; idx += 256) s_fc[idx / 3][idx % 3] = frac[b * 72 + idx];
    for (int idx = tid; idx < 768; idx += 256) {
        int row = idx >> 5, c8 = idx & 31;
        *(uint4*)&s_pJ[row][c8 * 8] = *(const uint4*)&partjh[row * 256 + c8 * 8];
    }
    if (tid < 64) {
        int row = tid >> 5, c8 = tid & 31;
        *(uint4*)&s_pI[row][c8 * 8] = *(const uint4*)&partih[row * 256 + c8 * 8];
    }
    __syncthreads();
    for (int idx = tid; idx < 3072; idx += 256) {
        int row = idx >> 6, k = idx & 63;
        unsigned short v = 0;
        if (k < 60) {
            int kk = (k < 30) ? k : k - 30;
            int d = kk / 10, f = kk % 10;
            int hi = (row >= 24);
            int j = row - (hi ? 24 : 0);
            float fd = s_fc[j][d] - s_fc[i0 + hi][d];
            fd -= floorf(fd);
            float ang = fd * (6.283185307179586f * (float)f);
            v = f2bf((k < 30) ? __sinf(ang) : __cosf(ang));
        }
        s_u[(row << 6) + (((k >> 3) ^ (row & 7)) << 3) + (k & 7)] = v;
    }
    __syncthreads();

    const unsigned short* wsu = (const unsigned short*)ws;
    const unsigned short* pw1d = wsu + (size_t)OFF_PW1D * 2 + (size_t)l * 16384;
    f32x4 acc[3][4] = {};
    for (int ks = 0; ks < 2; ks++) {
        bf16x8 a[3];
        int kb = ks * 4 + g;
#pragma unroll
        for (int mt = 0; mt < 3; mt++) {
            int row = mt * 16 + l15;
            a[mt] = *(const bf16x8*)&s_u[(row << 6) + ((kb ^ (row & 7)) << 3)];
        }
#pragma unroll
        for (int nt = 0; nt < 4; nt++) {
            bf16x8 bf = *(const bf16x8*)&pw1d[((size_t)(ks * 16 + w * 4 + nt) * 64 + ln) * 8];
#pragma unroll
            for (int mt = 0; mt < 3; mt++)
                acc[mt][nt] = __builtin_amdgcn_mfma_f32_16x16x32_bf16(a[mt], bf, acc[mt][nt], 0, 0, 0);
        }
    }
    __syncthreads();
    float pIv[2][4];
#pragma unroll
    for (int hi = 0; hi < 2; hi++)
#pragma unroll
        for (int nt = 0; nt < 4; nt++) pIv[hi][nt] = bf2f(s_pI[hi][w * 64 + nt * 16 + l15]);
#pragma unroll
    for (int mt = 0; mt < 3; mt++)
#pragma unroll
        for (int nt = 0; nt < 4; nt++) {
            int col = w * 64 + nt * 16 + l15;
#pragma unroll
            for (int r = 0; r < 4; r++) {
                int row = mt * 16 + 4 * g + r;
                int hi = (row >= 24);
                int j = row - 24 * hi;
                float v = acc[mt][nt][r] + pIv[hi][nt] + bf2f(s_pJ[j][col]);
                s_u[(row << 8) + ((((col >> 3) ^ (row & 7))) << 3) + (col & 7)] = f2bf(silu_f(v));
            }
        }
    __syncthreads();
    const unsigned short* pw2 = wsu + (size_t)OFF_PW2 * 2 + (size_t)l * 65536;
    f32x4 acc2[3][4] = {};
    for (int ks = 0; ks < 8; ks++) {
        bf16x8 a[3];
        int kb = ks * 4 + g;
#pragma unroll
        for (int mt = 0; mt < 3; mt++) {
            int row = mt * 16 + l15;
            a[mt] = *(const bf16x8*)&s_u[(row << 8) + ((kb ^ (row & 7)) << 3)];
        }
#pragma unroll
        for (int nt = 0; nt < 4; nt++) {
            bf16x8 bf = *(const bf16x8*)&pw2[((size_t)(ks * 16 + w * 4 + nt) * 64 + ln) * 8];
#pragma unroll
            for (int mt = 0; mt < 3; mt++)
                acc2[mt][nt] = __builtin_amdgcn_mfma_f32_16x16x32_bf16(a[mt], bf, acc2[mt][nt], 0, 0, 0);
        }
    }
    float s0[4] = {}, s1[4] = {};
#pragma unroll
    for (int nt = 0; nt < 4; nt++) {
        int col = w * 64 + nt * 16 + l15;
        float b2 = eb2[l * 256 + col];
#pragma unroll
        for (int r = 0; r < 4; r++) s0[nt] += silu_f(acc2[0][nt][r] + b2);
        float m = 0.f;
#pragma unroll
        for (int r = 0; r < 4; r++) m += silu_f(acc2[1][nt][r] + b2);
        if (g < 2) s0[nt] += m; else s1[nt] += m;
#pragma unroll
        for (int r = 0; r < 4; r++) s1[nt] += silu_f(acc2[2][nt][r] + b2);
    }
#pragma unroll
    for (int nt = 0; nt < 4; nt++) {
        s0[nt] += __shfl_xor(s0[nt], 16);
        s0[nt] += __shfl_xor(s0[nt], 32);
        s1[nt] += __shfl_xor(s1[nt], 16);
        s1[nt] += __shfl_xor(s1[nt], 32);
    }
    unsigned short* aggh = (unsigned short*)ws + (size_t)OFF_AGGH * 2;
    if (g == 0) {
#pragma unroll
        for (int nt = 0; nt < 4; nt++) {
            int col = w * 64 + nt * 16 + l15;
            aggh[(size_t)(b * 24 + i0) * 256 + col]     = f2bf(s0[nt] * (1.0f / 24.0f));
            aggh[(size_t)(b * 24 + i0 + 1) * 256 + col] = f2bf(s1[nt] * (1.0f / 24.0f));
        }
    }
}

// ---------------- tail: node-MLP(3) + types + coords + nf-out, 16 nodes/block ----------------
__global__ void __launch_bounds__(256) k_tail(const float* nb1, const float* nb2,
                                              const float* b_type, const float* w_coord,
                                              float* ws, float* out) {
    __shared__ __align__(16) unsigned short s_in[16][536];
    __shared__ __align__(16) unsigned short s_h[16][264];
    __shared__ __align__(16) unsigned short s_a[16][264];
    __shared__ float s_nf[16][260];
    int tid = threadIdx.x, w = tid >> 6, ln = tid & 63;
    int l15 = ln & 15, g = ln >> 4;
    int n0 = blockIdx.x * 16;
    const unsigned short* wsu = (const unsigned short*)ws;
    const int lp = 3;
    const unsigned short* nfmidh = wsu + (size_t)OFF_NFMIDH * 2;
    const unsigned short* aggh   = wsu + (size_t)OFF_AGGH * 2;
#pragma unroll
    for (int t = 0; t < 2; t++) {
        int idx = tid + t * 256;
        int row = idx >> 5, c8 = idx & 31;
        *(uint4*)&s_in[row][c8 * 8]       = *(const uint4*)&nfmidh[(size_t)(n0 + row) * 256 + c8 * 8];
        *(uint4*)&s_in[row][256 + c8 * 8] = *(const uint4*)&aggh[(size_t)(n0 + row) * 256 + c8 * 8];
    }
    __syncthreads();
    const unsigned short* p1 = wsu + (size_t)OFF_PNW1 * 2 + (size_t)lp * 131072;
    f32x4 acc[4] = {};
    for (int ks = 0; ks < 16; ks++) {
        bf16x8 a = *(const bf16x8*)&s_in[l15][ks * 32 + g * 8];
#pragma unroll
        for (int nt = 0; nt < 4; nt++) {
            bf16x8 bf = *(const bf16x8*)&p1[((size_t)(ks * 16 + w * 4 + nt) * 64 + ln) * 8];
            acc[nt] = __builtin_amdgcn_mfma_f32_16x16x32_bf16(a, bf, acc[nt], 0, 0, 0);
        }
    }
#pragma unroll
    for (int nt = 0; nt < 4; nt++) {
        int col = w * 64 + nt * 16 + l15;
        float b1 = nb1[lp * 256 + col];
#pragma unroll
        for (int r = 0; r < 4; r++) s_h[4 * g + r][col] = f2bf(silu_f(acc[nt][r] + b1));
    }
    __syncthreads();
    const unsigned short* p2 = wsu + (size_t)OFF_PNW2 * 2 + (size_t)lp * 65536;
    f32x4 a2[4] = {};
    for (int ks = 0; ks < 8; ks++) {
        bf16x8 a = *(const bf16x8*)&s_h[l15][ks * 32 + g * 8];
#pragma unroll
        for (int nt = 0; nt < 4; nt++) {
            bf16x8 bf = *(const bf16x8*)&p2[((size_t)(ks * 16 + w * 4 + nt) * 64 + ln) * 8];
            a2[nt] = __builtin_amdgcn_mfma_f32_16x16x32_bf16(a, bf, a2[nt], 0, 0, 0);
        }
    }
#pragma unroll
    for (int nt = 0; nt < 4; nt++) {
        int col = w * 64 + nt * 16 + l15;
        float b2 = nb2[lp * 256 + col];
#pragma unroll
        for (int r = 0; r < 4; r++) {
            int row = 4 * g + r, n = n0 + row;
            float v = bf2f(s_in[row][col]) + silu_f(a2[nt][r] + b2);
            s_nf[row][col] = v;
            s_a[row][col] = f2bf(v);
            out[OUT_NF + (size_t)n * 256 + col] = v;
        }
    }
    __syncthreads();
    // types GEMM: [16 x 256] @ [256 x 112] (cols >=103 dropped)
    const unsigned short* pt = wsu + (size_t)OFF_PWTYPE * 2;
    f32x4 at2[2] = {};
    for (int ks = 0; ks < 8; ks++) {
        bf16x8 a = *(const bf16x8*)&s_a[l15][ks * 32 + g * 8];
#pragma unroll
        for (int q = 0; q < 2; q++) {
            int nt = w + 4 * q;
            if (nt < 7) {
                bf16x8 bf = *(const bf16x8*)&pt[((size_t)(ks * 7 + nt) * 64 + ln) * 8];
                at2[q] = __builtin_amdgcn_mfma_f32_16x16x32_bf16(a, bf, at2[q], 0, 0, 0);
            }
        }
    }
#pragma unroll
    for (int q = 0; q < 2; q++) {
        int nt = w + 4 * q;
        if (nt < 7) {
            int a_col = nt * 16 + l15;
            if (a_col < 103) {
                float bt = b_type[a_col];
#pragma unroll
                for (int r = 0; r < 4; r++) {
                    int n = n0 + 4 * g + r;
                    out[OUT_TYPES + (size_t)n * 103 + a_col] = at2[q][r] + bt;
                }
            }
        }
    }
    // coords
    if (tid < 48) {
        int p = tid / 3, cc = tid % 3;
        float a0 = 0.f;
        for (int k = 0; k < 256; k++) a0 += s_nf[p][k] * w_coord[cc * 256 + k];
        out[OUT_COORD + (size_t)(n0 + p) * 3 + cc] = a0;
    }
}

// ---------------- lattice_out (reads nf from d_out at OUT_NF) ----------------
__global__ void k_out_graph(const float* lattices, const float* w_latt, const float* out_nf, float* out) {
    __shared__ float gf[256];
    __shared__ float lo[9];
    int b = blockIdx.x, h = threadIdx.x;
    float g = 0.f;
#pragma unroll
    for (int i = 0; i < 24; i++) g += out_nf[OUT_NF + (size_t)(b * 24 + i) * 256 + h];
    gf[h] = g * (1.0f / 24.0f);
    __syncthreads();
    if (h < 9) {
        float a0 = 0.f;
        for (int k = 0; k < 256; k++) a0 += gf[k] * w_latt[h * 256 + k];
        lo[h] = a0;
    }
    __syncthreads();
    if (h < 9) {
        int i = h / 3, kk = h % 3;
        float a0 = 0.f;
#pragma unroll
        for (int j = 0; j < 3; j++) a0 += lo[i * 3 + j] * lattices[b * 9 + j * 3 + kk];
        out[OUT_LATT + b * 9 + h] = a0;
    }
}

extern "C" void kernel_launch(void* const* d_in, const int* in_sizes, int n_in,
                              void* d_out, int out_size, void* d_ws, size_t ws_size,
                              hipStream_t stream) {
    const float* atom_types = (const float*)d_in[0];
    const float* frac       = (const float*)d_in[1];
    const float* lattices   = (const float*)d_in[2];
    const float* t_in       = (const float*)d_in[3];
    const float* text       = (const float*)d_in[4];
    const float* w_emb      = (const float*)d_in[5];
    const float* b_emb      = (const float*)d_in[6];
    const float* w_cond     = (const float*)d_in[7];
    const float* b_cond     = (const float*)d_in[8];
    const float* w_proj     = (const float*)d_in[9];
    const float* b_proj     = (const float*)d_in[10];
    const float* film_g     = (const float*)d_in[11];
    const float* film_b     = (const float*)d_in[12];
    const float* ew1        = (const float*)d_in[13];
    const float* eb1        = (const float*)d_in[14];
    const float* ew2        = (const float*)d_in[15];
    const float* eb2        = (const float*)d_in[16];
    const float* nw1        = (const float*)d_in[17];
    const float* nb1        = (const float*)d_in[18];
    const float* nw2        = (const float*)d_in[19];
    const float* nb2        = (const float*)d_in[20];
    const float* w_coord    = (const float*)d_in[21];
    const float* w_latt     = (const float*)d_in[22];
    const float* w_type     = (const float*)d_in[23];
    const float* b_type     = (const float*)d_in[24];
    float* ws  = (float*)d_ws;
    float* out = (float*)d_out;

    k_prep<<<7700, 256, 0, stream>>>(w_emb, w_cond, w_proj, ew1, ew2, nw1, nw2, w_type, ws);
    k_setup<<<8, 256, 0, stream>>>(lattices, t_in, text, b_cond, ws);
    for (int l = 0; l < NLAYERS; l++) {
        k_fnf<<<N_ / 16, 256, 0, stream>>>(l, atom_types, b_emb, nb1, nb2,
                                           b_proj, film_g, film_b, eb1, ws);
        k_edge<<<N_ * 12 / 24, 256, 0, stream>>>(l, frac, eb2, ws);
    }
    k_tail<<<N_ / 16, 256, 0, stream>>>(nb1, nb2, b_type, w_coord, ws, out);
    k_out_graph<<<B_, 256, 0, stream>>>(lattices, w_latt, out, out);
}

// Round 8
// 348.841 us; speedup vs baseline: 7.4398x; 1.0777x over previous
//
#include <hip/hip_runtime.h>
#include <math.h>

// ---- problem constants ----
#define B_      128
#define A_      24
#define N_      3072     // B_*A_
#define NLAYERS 4

// ---- workspace layout (float-element offsets) ----
// NOTE: each [3072][256] bf16 buffer = 786432 ushorts = 393216 float slots.
#define OFF_COND    0         // [128][512] f32                      (65536)
#define OFF_LATW    65536     // [4][128][256] f32                   (131072)
#define OFF_NFMIDH  196608    // [3072][256] bf16                    (393216)
#define OFF_AGGH    589824    // [3072][256] bf16                    (393216)
#define OFF_PARTIH  983040    // [3072][256] bf16 (incl. eb1+latW)   (393216)
#define OFF_PARTJH  1376256   // [3072][256] bf16                    (393216)
#define OFF_W1LATT  1769472   // [4][9][256] f32                     (9216)
#define OFF_PW1A    1778688   // [4][8][16][64][8] bf16              (131072)
#define OFF_PW1B    1909760   //                                     (131072)
#define OFF_PW1D    2040832   // [4][2][16][64][8] bf16              (32768)
#define OFF_PW2     2073600   // [4][8][16][64][8] bf16              (131072)
#define OFF_PWPROJ  2204672   // [8][16][64][8] bf16                 (32768)
#define OFF_PNW1    2237440   // [4][16][16][64][8] bf16             (262144)
#define OFF_PNW2    2499584   // [4][8][16][64][8] bf16              (131072)
#define OFF_PWEMB   2630656   // [4 ks][16 nt][64][8] bf16 (K pad)   (16384)
#define OFF_PWCOND  2647040   // [12 ks][32 nt][64][8] bf16 (K=384)  (98304)
#define OFF_PWTYPE  2745344   // [8 ks][7 nt][64][8] bf16 (N pad)    (14336)
// end 2759680 floats ~ 10.5 MiB

// output offsets (floats): types | lattice | coords | nf
#define OUT_TYPES  0
#define OUT_LATT   316416
#define OUT_COORD  317568
#define OUT_NF     326784

typedef __attribute__((ext_vector_type(8))) short bf16x8;
typedef __attribute__((ext_vector_type(4))) float f32x4;

__device__ __forceinline__ float silu_f(float x) { return x / (1.0f + __expf(-x)); }
__device__ __forceinline__ unsigned short f2bf(float x) {
    unsigned int u = __float_as_uint(x);
    return (unsigned short)((u + 0x7FFFu + ((u >> 16) & 1u)) >> 16);
}
__device__ __forceinline__ float bf2f(unsigned short h) {
    return __uint_as_float(((unsigned int)h) << 16);
}

// ---------------- weight packs ----------------
// generic pack: pack[((ks*NT + nt)*64 + lane)*8 + j] = W[k][n],
//   k = ks*32 + (lane>>4)*8 + j,  n = nt*16 + (lane&15)
__global__ void k_prep(const float* w_emb, const float* w_cond, const float* w_proj,
                       const float* ew1, const float* ew2, const float* nw1, const float* nw2,
                       const float* w_type, float* ws) {
    int idx = blockIdx.x * blockDim.x + threadIdx.x;
    unsigned short* pu = (unsigned short*)ws;
    int i = idx;
    if (i < 9216)   { int l = i / 2304, r = (i % 2304) / 256, h = i % 256;
                      ws[OFF_W1LATT + i] = ew1[((size_t)l * 256 + h) * 581 + 512 + r]; return; }        i -= 9216;
    if (i < 262144) { int l = i >> 16, r = i & 65535, ks = r >> 13, r2 = r & 8191,
                      nt = r2 >> 9, r3 = r2 & 511, lane = r3 >> 3, j = r3 & 7;
                      int k = ks * 32 + (lane >> 4) * 8 + j, n = nt * 16 + (lane & 15);
                      pu[(size_t)OFF_PW1A * 2 + i] = f2bf(ew1[((size_t)l * 256 + n) * 581 + k]); return; } i -= 262144;
    if (i < 262144) { int l = i >> 16, r = i & 65535, ks = r >> 13, r2 = r & 8191,
                      nt = r2 >> 9, r3 = r2 & 511, lane = r3 >> 3, j = r3 & 7;
                      int k = ks * 32 + (lane >> 4) * 8 + j, n = nt * 16 + (lane & 15);
                      pu[(size_t)OFF_PW1B * 2 + i] = f2bf(ew1[((size_t)l * 256 + n) * 581 + 256 + k]); return; } i -= 262144;
    if (i < 65536)  { int l = i >> 14, r = i & 16383, ks = r >> 13, r2 = r & 8191,
                      nt = r2 >> 9, r3 = r2 & 511, lane = r3 >> 3, j = r3 & 7;
                      int kp = ks * 32 + (lane >> 4) * 8 + j, n = nt * 16 + (lane & 15);
                      float v = (kp < 60) ? ew1[((size_t)l * 256 + n) * 581 + 521 + kp] : 0.0f;
                      pu[(size_t)OFF_PW1D * 2 + i] = f2bf(v); return; }                                  i -= 65536;
    if (i < 262144) { int l = i >> 16, r = i & 65535, ks = r >> 13, r2 = r & 8191,
                      nt = r2 >> 9, r3 = r2 & 511, lane = r3 >> 3, j = r3 & 7;
                      int k = ks * 32 + (lane >> 4) * 8 + j, n = nt * 16 + (lane & 15);
                      pu[(size_t)OFF_PW2 * 2 + i] = f2bf(ew2[((size_t)l * 256 + n) * 256 + k]); return; } i -= 262144;
    if (i < 65536)  { int ks = i >> 13, r2 = i & 8191,
                      nt = r2 >> 9, r3 = r2 & 511, lane = r3 >> 3, j = r3 & 7;
                      int k = ks * 32 + (lane >> 4) * 8 + j, n = nt * 16 + (lane & 15);
                      pu[(size_t)OFF_PWPROJ * 2 + i] = f2bf(w_proj[(size_t)n * 256 + k]); return; }      i -= 65536;
    if (i < 524288) { int l = i >> 17, r = i & 131071, ks = r >> 13, r2 = r & 8191,
                      nt = r2 >> 9, r3 = r2 & 511, lane = r3 >> 3, j = r3 & 7;
                      int k = ks * 32 + (lane >> 4) * 8 + j, n = nt * 16 + (lane & 15);
                      pu[(size_t)OFF_PNW1 * 2 + i] = f2bf(nw1[((size_t)l * 256 + n) * 512 + k]); return; } i -= 524288;
    if (i < 262144) { int l = i >> 16, r = i & 65535, ks = r >> 13, r2 = r & 8191,
                      nt = r2 >> 9, r3 = r2 & 511, lane = r3 >> 3, j = r3 & 7;
                      int k = ks * 32 + (lane >> 4) * 8 + j, n = nt * 16 + (lane & 15);
                      pu[(size_t)OFF_PNW2 * 2 + i] = f2bf(nw2[((size_t)l * 256 + n) * 256 + k]); return; } i -= 262144;
    if (i < 32768)  { int ks = i >> 13, r2 = i & 8191,
                      nt = r2 >> 9, r3 = r2 & 511, lane = r3 >> 3, j = r3 & 7;
                      int k = ks * 32 + (lane >> 4) * 8 + j, n = nt * 16 + (lane & 15);
                      float v = (k < 103) ? w_emb[(size_t)n * 103 + k] : 0.0f;
                      pu[(size_t)OFF_PWEMB * 2 + i] = f2bf(v); return; }                                 i -= 32768;
    if (i < 196608) { int ks = i / 16384, r2 = i & 16383,
                      nt = r2 >> 9, r3 = r2 & 511, lane = r3 >> 3, j = r3 & 7;
                      int k = ks * 32 + (lane >> 4) * 8 + j, n = nt * 16 + (lane & 15);
                      pu[(size_t)OFF_PWCOND * 2 + i] = f2bf(w_cond[(size_t)n * 384 + k]); return; }      i -= 196608;
    { int ks = i / 3584, r2 = i % 3584,
      nt = r2 >> 9, r3 = r2 & 511, lane = r3 >> 3, j = r3 & 7;
      int k = ks * 32 + (lane >> 4) * 8 + j, a = nt * 16 + (lane & 15);
      float v = (a < 103) ? w_type[(size_t)a * 256 + k] : 0.0f;
      pu[(size_t)OFF_PWTYPE * 2 + i] = f2bf(v); }
}

// ---------------- setup: latips + latW + cond (MFMA), 8 blocks x 16 graphs ----------------
__global__ void __launch_bounds__(256) k_setup(const float* lat, const float* t_in, const float* tx,
                                               const float* b_cond, float* ws) {
    __shared__ __align__(16) unsigned short s_ct[16][392];
    __shared__ float s_lat[16][9];
    int tid = threadIdx.x, w = tid >> 6, ln = tid & 63;
    int l15 = ln & 15, g = ln >> 4;
    int g0 = blockIdx.x * 16;
    if (tid < 144) {
        int gl = tid / 9, r = tid % 9, ii = r / 3, kk = r % 3;
        const float* L = lat + (g0 + gl) * 9;
        s_lat[gl][r] = L[ii*3+0]*L[kk*3+0] + L[ii*3+1]*L[kk*3+1] + L[ii*3+2]*L[kk*3+2];
    }
    for (int idx = tid; idx < 16 * 384; idx += 256) {
        int row = idx / 384, k = idx % 384;
        float v = (k < 256) ? t_in[(size_t)(g0 + row) * 256 + k] : tx[(size_t)(g0 + row) * 128 + (k - 256)];
        s_ct[row][k] = f2bf(v);
    }
    __syncthreads();
    for (int idx = tid; idx < 16384; idx += 256) {
        int l = idx >> 12, gl = (idx >> 8) & 15, h = idx & 255;
        float a = 0.f;
#pragma unroll
        for (int r = 0; r < 9; r++) a += s_lat[gl][r] * ws[OFF_W1LATT + (l * 9 + r) * 256 + h];
        ws[OFF_LATW + (size_t)(l * 128 + g0 + gl) * 256 + h] = a;
    }
    const unsigned short* pc = (const unsigned short*)ws + (size_t)OFF_PWCOND * 2;
    f32x4 acc[8] = {};
    for (int ks = 0; ks < 12; ks++) {
        bf16x8 a = *(const bf16x8*)&s_ct[l15][ks * 32 + g * 8];
#pragma unroll
        for (int q = 0; q < 8; q++) {
            int nt = w * 8 + q;
            bf16x8 bf = *(const bf16x8*)&pc[((size_t)(ks * 32 + nt) * 64 + ln) * 8];
            acc[q] = __builtin_amdgcn_mfma_f32_16x16x32_bf16(a, bf, acc[q], 0, 0, 0);
        }
    }
#pragma unroll
    for (int q = 0; q < 8; q++) {
        int col = w * 128 + q * 16 + l15;
        float bc = b_cond[col];
#pragma unroll
        for (int r = 0; r < 4; r++) {
            int gg = g0 + 4 * g + r;
            ws[OFF_COND + (size_t)gg * 512 + col] = silu_f(acc[q][r] + bc);
        }
    }
}

// ---------------- fused node-MLP(l-1) [or embed] + FiLM(l) + PartI/PartJ(l) ----------------
// 512 threads / 8 waves; wave w owns N-tiles nt16 = 2w, 2w+1 (cols 32w..32w+31)
__global__ void __launch_bounds__(512) k_fnf(int l, const float* at, const float* b_emb,
                                             const float* nb1, const float* nb2,
                                             const float* b_proj, const float* film_g, const float* film_b,
                                             const float* eb1, float* ws) {
    __shared__ __align__(16) unsigned short s_in[16][536];
    __shared__ __align__(16) unsigned short s_h[16][264];
    __shared__ __align__(16) unsigned short s_a[16][264];
    __shared__ float s_nf[16][260];
    __shared__ float s_mu[16], s_rs[16];
    float (*s_c)[268] = (float(*)[268])&s_in[0][0];   // aliased over s_in (used after node phase)
    int tid = threadIdx.x, w = tid >> 6, ln = tid & 63;
    int l15 = ln & 15, g = ln >> 4;
    int n0 = blockIdx.x * 16;
    const unsigned short* wsu = (const unsigned short*)ws;
    unsigned short* wsw = (unsigned short*)ws;

    f32x4 accn[2] = {};
    if (l == 0) {
        // ---- embed: nf = at @ w_emb^T + b_emb ----
        for (int idx = tid; idx < 16 * 128; idx += 512) {
            int row = idx >> 7, k = idx & 127;
            s_in[row][k] = (k < 103) ? f2bf(at[(size_t)(n0 + row) * 103 + k]) : (unsigned short)0;
        }
        __syncthreads();
        const unsigned short* pe = wsu + (size_t)OFF_PWEMB * 2;
        for (int ks = 0; ks < 4; ks++) {
            bf16x8 a = *(const bf16x8*)&s_in[l15][ks * 32 + g * 8];
#pragma unroll
            for (int q = 0; q < 2; q++) {
                bf16x8 bf = *(const bf16x8*)&pe[((size_t)(ks * 16 + 2 * w + q) * 64 + ln) * 8];
                accn[q] = __builtin_amdgcn_mfma_f32_16x16x32_bf16(a, bf, accn[q], 0, 0, 0);
            }
        }
        __syncthreads();   // all embed A reads done before s_nf/s_a writes (s_nf separate, s_a separate; safe anyway)
#pragma unroll
        for (int q = 0; q < 2; q++) {
            int col = w * 32 + q * 16 + l15;
            float be = b_emb[col];
#pragma unroll
            for (int r = 0; r < 4; r++) {
                int row = 4 * g + r;
                float v = accn[q][r] + be;
                s_nf[row][col] = v;
                s_a[row][col] = f2bf(v);
            }
        }
    } else {
        // ---- node MLP of layer l-1 ----
        int lp = l - 1;
        const unsigned short* nfmidh = wsu + (size_t)OFF_NFMIDH * 2;
        const unsigned short* aggh   = wsu + (size_t)OFF_AGGH * 2;
        {
            int row = tid >> 5, c8 = tid & 31;
            *(uint4*)&s_in[row][c8 * 8]       = *(const uint4*)&nfmidh[(size_t)(n0 + row) * 256 + c8 * 8];
            *(uint4*)&s_in[row][256 + c8 * 8] = *(const uint4*)&aggh[(size_t)(n0 + row) * 256 + c8 * 8];
        }
        __syncthreads();
        const unsigned short* p1 = wsu + (size_t)OFF_PNW1 * 2 + (size_t)lp * 131072;
        f32x4 acc[2] = {};
        for (int ks = 0; ks < 16; ks++) {
            bf16x8 a = *(const bf16x8*)&s_in[l15][ks * 32 + g * 8];
#pragma unroll
            for (int q = 0; q < 2; q++) {
                bf16x8 bf = *(const bf16x8*)&p1[((size_t)(ks * 16 + 2 * w + q) * 64 + ln) * 8];
                acc[q] = __builtin_amdgcn_mfma_f32_16x16x32_bf16(a, bf, acc[q], 0, 0, 0);
            }
        }
#pragma unroll
        for (int q = 0; q < 2; q++) {
            int col = w * 32 + q * 16 + l15;
            float b1 = nb1[lp * 256 + col];
#pragma unroll
            for (int r = 0; r < 4; r++) s_h[4 * g + r][col] = f2bf(silu_f(acc[q][r] + b1));
        }
        __syncthreads();
        const unsigned short* p2 = wsu + (size_t)OFF_PNW2 * 2 + (size_t)lp * 65536;
        for (int ks = 0; ks < 8; ks++) {
            bf16x8 a = *(const bf16x8*)&s_h[l15][ks * 32 + g * 8];
#pragma unroll
            for (int q = 0; q < 2; q++) {
                bf16x8 bf = *(const bf16x8*)&p2[((size_t)(ks * 16 + 2 * w + q) * 64 + ln) * 8];
                accn[q] = __builtin_amdgcn_mfma_f32_16x16x32_bf16(a, bf, accn[q], 0, 0, 0);
            }
        }
#pragma unroll
        for (int q = 0; q < 2; q++) {
            int col = w * 32 + q * 16 + l15;
            float b2 = nb2[lp * 256 + col];
#pragma unroll
            for (int r = 0; r < 4; r++) {
                int row = 4 * g + r;
                float v = bf2f(s_in[row][col]) + silu_f(accn[q][r] + b2);
                s_nf[row][col] = v;
                s_a[row][col] = f2bf(v);
            }
        }
    }
    __syncthreads();
    // ---- proj GEMM: [16 x 256] @ [256 x 256] ----
    const unsigned short* pwp = wsu + (size_t)OFF_PWPROJ * 2;
    f32x4 accp[2] = {};
    for (int ks = 0; ks < 8; ks++) {
        bf16x8 a = *(const bf16x8*)&s_a[l15][ks * 32 + g * 8];
#pragma unroll
        for (int q = 0; q < 2; q++) {
            bf16x8 bf = *(const bf16x8*)&pwp[((size_t)(ks * 16 + 2 * w + q) * 64 + ln) * 8];
            accp[q] = __builtin_amdgcn_mfma_f32_16x16x32_bf16(a, bf, accp[q], 0, 0, 0);
        }
    }
    __syncthreads();  // s_in (node phase) fully read; s_c (alias) may be written
#pragma unroll
    for (int q = 0; q < 2; q++) {
        int col = w * 32 + q * 16 + l15;
        float bp = b_proj[col];
#pragma unroll
        for (int r = 0; r < 4; r++) s_c[4 * g + r][col] = accp[q][r] + bp;
    }
    __syncthreads();
    // ---- LN stats: wave w handles rows 2w, 2w+1 ----
    for (int r2 = 0; r2 < 2; r2++) {
        int row = w * 2 + r2;
        float s = 0.f, q = 0.f;
        for (int c = ln; c < 256; c += 64) { float v = s_c[row][c]; s += v; q += v * v; }
#pragma unroll
        for (int o = 1; o < 64; o <<= 1) { s += __shfl_xor(s, o); q += __shfl_xor(q, o); }
        if (ln == 0) {
            float mu = s * (1.0f / 256.0f);
            float var = q * (1.0f / 256.0f) - mu * mu;
            s_mu[row] = mu; s_rs[row] = rsqrtf(var + 1e-5f);
        }
    }
    __syncthreads();
    // ---- FiLM epilogue: col = tid&255, rows (tid>>8) + 2t ----
    {
        int col = tid & 255, rb = tid >> 8;
        float gg = film_g[col], bb = film_b[col];
        unsigned short* nfmidh = wsw + (size_t)OFF_NFMIDH * 2;
#pragma unroll
        for (int t = 0; t < 8; t++) {
            int row = rb + 2 * t;
            int n = n0 + row, b = n / 24;
            float sc = ws[OFF_COND + (size_t)b * 512 + col];
            float sh = ws[OFF_COND + (size_t)b * 512 + 256 + col];
            float yn = (s_c[row][col] - s_mu[row]) * s_rs[row] * gg + bb;
            float outv = s_nf[row][col] + silu_f(yn * sc + sh);
            unsigned short ob = f2bf(outv);
            nfmidh[(size_t)n * 256 + col] = ob;
            s_a[row][col] = ob;
        }
    }
    __syncthreads();
    // ---- PartI/PartJ GEMMs ----
    const unsigned short* pA = wsu + (size_t)OFF_PW1A * 2 + (size_t)l * 65536;
    const unsigned short* pB = wsu + (size_t)OFF_PW1B * 2 + (size_t)l * 65536;
    f32x4 aI[2] = {}, aJ[2] = {};
    for (int ks = 0; ks < 8; ks++) {
        bf16x8 a = *(const bf16x8*)&s_a[l15][ks * 32 + g * 8];
#pragma unroll
        for (int q = 0; q < 2; q++) {
            bf16x8 bi = *(const bf16x8*)&pA[((size_t)(ks * 16 + 2 * w + q) * 64 + ln) * 8];
            bf16x8 bj = *(const bf16x8*)&pB[((size_t)(ks * 16 + 2 * w + q) * 64 + ln) * 8];
            aI[q] = __builtin_amdgcn_mfma_f32_16x16x32_bf16(a, bi, aI[q], 0, 0, 0);
            aJ[q] = __builtin_amdgcn_mfma_f32_16x16x32_bf16(a, bj, aJ[q], 0, 0, 0);
        }
    }
    unsigned short* partih = wsw + (size_t)OFF_PARTIH * 2;
    unsigned short* partjh = wsw + (size_t)OFF_PARTJH * 2;
#pragma unroll
    for (int q = 0; q < 2; q++) {
        int col = w * 32 + q * 16 + l15;
        float e1 = eb1[l * 256 + col];
#pragma unroll
        for (int r = 0; r < 4; r++) {
            int n = n0 + 4 * g + r;
            int gb = n / 24;
            float vi = aI[q][r] + e1 + ws[OFF_LATW + (size_t)(l * 128 + gb) * 256 + col];
            partih[(size_t)n * 256 + col] = f2bf(vi);
            partjh[(size_t)n * 256 + col] = f2bf(aJ[q][r]);
        }
    }
}

// ---------------- fused edge pipeline (swizzled LDS, in-register aggregation) ----------------
__global__ void __launch_bounds__(256, 4) k_edge(int l, const float* frac, const float* eb2, float* ws) {
    __shared__ __align__(16) unsigned short s_u[48 * 256];   // ef1 (swizzled); demb aliased in first 6 KB
    __shared__ __align__(16) unsigned short s_pJ[24][264];
    __shared__ __align__(16) unsigned short s_pI[2][264];
    __shared__ float s_fc[24][3];
    int tid = threadIdx.x, w = tid >> 6, ln = tid & 63;
    int l15 = ln & 15, g = ln >> 4;
    int b = blockIdx.x & 127, c = blockIdx.x >> 7;
    int i0 = c * 2;

    const unsigned short* partjh = (const unsigned short*)ws + (size_t)OFF_PARTJH * 2 + (size_t)b * 24 * 256;
    const unsigned short* partih = (const unsigned short*)ws + (size_t)OFF_PARTIH * 2 + (size_t)(b * 24 + i0) * 256;
    for (int idx = tid; idx < 72; idx += 256) s_fc[idx / 3][idx % 3] = frac[b * 72 + idx];
    for (int idx = tid; idx < 768; idx += 256) {
        int row = idx >> 5, c8 = idx & 31;
        *(uint4*)&s_pJ[row][c8 * 8] = *(const uint4*)&partjh[row * 256 + c8 * 8];
    }
    if (tid < 64) {
        int row = tid >> 5, c8 = tid & 31;
        *(uint4*)&s_pI[row][c8 * 8] = *(const uint4*)&partih[row * 256 + c8 * 8];
    }
    __syncthreads();
    for (int idx = tid; idx < 3072; idx += 256) {
        int row = idx >> 6, k = idx & 63;
        unsigned short v = 0;
        if (k < 60) {
            int kk = (k < 30) ? k : k - 30;
            int d = kk / 10, f = kk % 10;
            int hi = (row >= 24);
            int j = row - (hi ? 24 : 0);
            float fd = s_fc[j][d] - s_fc[i0 + hi][d];
            fd -= floorf(fd);
            float ang = fd * (6.283185307179586f * (float)f);
            v = f2bf((k < 30) ? __sinf(ang) : __cosf(ang));
        }
        s_u[(row << 6) + (((k >> 3) ^ (row & 7)) << 3) + (k & 7)] = v;
    }
    __syncthreads();

    const unsigned short* wsu = (const unsigned short*)ws;
    const unsigned short* pw1d = wsu + (size_t)OFF_PW1D * 2 + (size_t)l * 16384;
    f32x4 acc[3][4] = {};
    for (int ks = 0; ks < 2; ks++) {
        bf16x8 a[3];
        int kb = ks * 4 + g;
#pragma unroll
        for (int mt = 0; mt < 3; mt++) {
            int row = mt * 16 + l15;
            a[mt] = *(const bf16x8*)&s_u[(row << 6) + ((kb ^ (row & 7)) << 3)];
        }
#pragma unroll
        for (int nt = 0; nt < 4; nt++) {
            bf16x8 bf = *(const bf16x8*)&pw1d[((size_t)(ks * 16 + w * 4 + nt) * 64 + ln) * 8];
#pragma unroll
            for (int mt = 0; mt < 3; mt++)
                acc[mt][nt] = __builtin_amdgcn_mfma_f32_16x16x32_bf16(a[mt], bf, acc[mt][nt], 0, 0, 0);
        }
    }
    __syncthreads();
    float pIv[2][4];
#pragma unroll
    for (int hi = 0; hi < 2; hi++)
#pragma unroll
        for (int nt = 0; nt < 4; nt++) pIv[hi][nt] = bf2f(s_pI[hi][w * 64 + nt * 16 + l15]);
#pragma unroll
    for (int mt = 0; mt < 3; mt++)
#pragma unroll
        for (int nt = 0; nt < 4; nt++) {
            int col = w * 64 + nt * 16 + l15;
#pragma unroll
            for (int r = 0; r < 4; r++) {
                int row = mt * 16 + 4 * g + r;
                int hi = (row >= 24);
                int j = row - 24 * hi;
                float v = acc[mt][nt][r] + pIv[hi][nt] + bf2f(s_pJ[j][col]);
                s_u[(row << 8) + ((((col >> 3) ^ (row & 7))) << 3) + (col & 7)] = f2bf(silu_f(v));
            }
        }
    __syncthreads();
    const unsigned short* pw2 = wsu + (size_t)OFF_PW2 * 2 + (size_t)l * 65536;
    f32x4 acc2[3][4] = {};
    for (int ks = 0; ks < 8; ks++) {
        bf16x8 a[3];
        int kb = ks * 4 + g;
#pragma unroll
        for (int mt = 0; mt < 3; mt++) {
            int row = mt * 16 + l15;
            a[mt] = *(const bf16x8*)&s_u[(row << 8) + ((kb ^ (row & 7)) << 3)];
        }
#pragma unroll
        for (int nt = 0; nt < 4; nt++) {
            bf16x8 bf = *(const bf16x8*)&pw2[((size_t)(ks * 16 + w * 4 + nt) * 64 + ln) * 8];
#pragma unroll
            for (int mt = 0; mt < 3; mt++)
                acc2[mt][nt] = __builtin_amdgcn_mfma_f32_16x16x32_bf16(a[mt], bf, acc2[mt][nt], 0, 0, 0);
        }
    }
    float s0[4] = {}, s1[4] = {};
#pragma unroll
    for (int nt = 0; nt < 4; nt++) {
        int col = w * 64 + nt * 16 + l15;
        float b2 = eb2[l * 256 + col];
#pragma unroll
        for (int r = 0; r < 4; r++) s0[nt] += silu_f(acc2[0][nt][r] + b2);
        float m = 0.f;
#pragma unroll
        for (int r = 0; r < 4; r++) m += silu_f(acc2[1][nt][r] + b2);
        if (g < 2) s0[nt] += m; else s1[nt] += m;
#pragma unroll
        for (int r = 0; r < 4; r++) s1[nt] += silu_f(acc2[2][nt][r] + b2);
    }
#pragma unroll
    for (int nt = 0; nt < 4; nt++) {
        s0[nt] += __shfl_xor(s0[nt], 16);
        s0[nt] += __shfl_xor(s0[nt], 32);
        s1[nt] += __shfl_xor(s1[nt], 16);
        s1[nt] += __shfl_xor(s1[nt], 32);
    }
    unsigned short* aggh = (unsigned short*)ws + (size_t)OFF_AGGH * 2;
    if (g == 0) {
#pragma unroll
        for (int nt = 0; nt < 4; nt++) {
            int col = w * 64 + nt * 16 + l15;
            aggh[(size_t)(b * 24 + i0) * 256 + col]     = f2bf(s0[nt] * (1.0f / 24.0f));
            aggh[(size_t)(b * 24 + i0 + 1) * 256 + col] = f2bf(s1[nt] * (1.0f / 24.0f));
        }
    }
}

// ---------------- tail: node-MLP(3) + types + coords + nf-out + lattice, graph-aligned ----------------
// 128 blocks x 512 threads; 24 real rows padded to M=32 (pad rows' outputs discarded)
__global__ void __launch_bounds__(512) k_tail(const float* nb1, const float* nb2,
                                              const float* b_type, const float* w_coord,
                                              const float* lattices, const float* w_latt,
                                              float* ws, float* out) {
    __shared__ __align__(16) unsigned short s_in[32][536];
    __shared__ __align__(16) unsigned short s_h[32][264];
    __shared__ float gf[256];
    __shared__ float lo[9];
    float (*s_nf)[260] = (float(*)[260])&s_in[0][0];       // alias: valid after residual reads
    unsigned short (*s_a)[264] = s_h;                       // alias: valid after GEMM2 reads
    int tid = threadIdx.x, w = tid >> 6, ln = tid & 63;
    int l15 = ln & 15, g = ln >> 4;
    int b = blockIdx.x, n0 = b * 24;
    const unsigned short* wsu = (const unsigned short*)ws;
    const int lp = 3;
    const unsigned short* nfmidh = wsu + (size_t)OFF_NFMIDH * 2;
    const unsigned short* aggh   = wsu + (size_t)OFF_AGGH * 2;
    for (int idx = tid; idx < 1024; idx += 512) {
        int row = idx >> 5, c8 = idx & 31;
        int rr = (row < 24) ? row : 0;
        *(uint4*)&s_in[row][c8 * 8]       = *(const uint4*)&nfmidh[(size_t)(n0 + rr) * 256 + c8 * 8];
        *(uint4*)&s_in[row][256 + c8 * 8] = *(const uint4*)&aggh[(size_t)(n0 + rr) * 256 + c8 * 8];
    }
    __syncthreads();
    // GEMM1: [32 x 512] @ [512 x 256]; wave w -> nt16 = 2w,2w+1
    const unsigned short* p1 = wsu + (size_t)OFF_PNW1 * 2 + (size_t)lp * 131072;
    f32x4 acc[2][2] = {};
    for (int ks = 0; ks < 16; ks++) {
        bf16x8 a0 = *(const bf16x8*)&s_in[l15][ks * 32 + g * 8];
        bf16x8 a1 = *(const bf16x8*)&s_in[16 + l15][ks * 32 + g * 8];
#pragma unroll
        for (int q = 0; q < 2; q++) {
            bf16x8 bf = *(const bf16x8*)&p1[((size_t)(ks * 16 + 2 * w + q) * 64 + ln) * 8];
            acc[0][q] = __builtin_amdgcn_mfma_f32_16x16x32_bf16(a0, bf, acc[0][q], 0, 0, 0);
            acc[1][q] = __builtin_amdgcn_mfma_f32_16x16x32_bf16(a1, bf, acc[1][q], 0, 0, 0);
        }
    }
#pragma unroll
    for (int q = 0; q < 2; q++) {
        int col = w * 32 + q * 16 + l15;
        float b1 = nb1[lp * 256 + col];
#pragma unroll
        for (int mt = 0; mt < 2; mt++)
#pragma unroll
            for (int r = 0; r < 4; r++) s_h[mt * 16 + 4 * g + r][col] = f2bf(silu_f(acc[mt][q][r] + b1));
    }
    __syncthreads();
    // GEMM2: [32 x 256] @ [256 x 256]
    const unsigned short* p2 = wsu + (size_t)OFF_PNW2 * 2 + (size_t)lp * 65536;
    f32x4 a2[2][2] = {};
    for (int ks = 0; ks < 8; ks++) {
        bf16x8 a0 = *(const bf16x8*)&s_h[l15][ks * 32 + g * 8];
        bf16x8 a1 = *(const bf16x8*)&s_h[16 + l15][ks * 32 + g * 8];
#pragma unroll
        for (int q = 0; q < 2; q++) {
            bf16x8 bf = *(const bf16x8*)&p2[((size_t)(ks * 16 + 2 * w + q) * 64 + ln) * 8];
            a2[0][q] = __builtin_amdgcn_mfma_f32_16x16x32_bf16(a0, bf, a2[0][q], 0, 0, 0);
            a2[1][q] = __builtin_amdgcn_mfma_f32_16x16x32_bf16(a1, bf, a2[1][q], 0, 0, 0);
        }
    }
    // read residuals before aliasing s_in
    float res[2][2][4];
#pragma unroll
    for (int q = 0; q < 2; q++) {
        int col = w * 32 + q * 16 + l15;
#pragma unroll
        for (int mt = 0; mt < 2; mt++)
#pragma unroll
            for (int r = 0; r < 4; r++) res[mt][q][r] = bf2f(s_in[mt * 16 + 4 * g + r][col]);
    }
    __syncthreads();   // all s_in / s_h reads done; aliases become writable
#pragma unroll
    for (int q = 0; q < 2; q++) {
        int col = w * 32 + q * 16 + l15;
        float b2 = nb2[lp * 256 + col];
#pragma unroll
        for (int mt = 0; mt < 2; mt++)
#pragma unroll
            for (int r = 0; r < 4; r++) {
                int row = mt * 16 + 4 * g + r;
                float v = res[mt][q][r] + silu_f(a2[mt][q][r] + b2);
                if (row < 24) {
                    s_nf[row][col] = v;
                    out[OUT_NF + (size_t)(n0 + row) * 256 + col] = v;
                }
                s_a[row][col] = f2bf(v);
            }
    }
    __syncthreads();
    // types GEMM: [32 x 256] @ [256 x 112] — waves 0..6
    if (w < 7) {
        const unsigned short* pt = wsu + (size_t)OFF_PWTYPE * 2;
        f32x4 at2[2] = {};
        for (int ks = 0; ks < 8; ks++) {
            bf16x8 a0 = *(const bf16x8*)&s_a[l15][ks * 32 + g * 8];
            bf16x8 a1 = *(const bf16x8*)&s_a[16 + l15][ks * 32 + g * 8];
            bf16x8 bf = *(const bf16x8*)&pt[((size_t)(ks * 7 + w) * 64 + ln) * 8];
            at2[0] = __builtin_amdgcn_mfma_f32_16x16x32_bf16(a0, bf, at2[0], 0, 0, 0);
            at2[1] = __builtin_amdgcn_mfma_f32_16x16x32_bf16(a1, bf, at2[1], 0, 0, 0);
        }
        int a_col = w * 16 + l15;
        if (a_col < 103) {
            float bt = b_type[a_col];
#pragma unroll
            for (int mt = 0; mt < 2; mt++)
#pragma unroll
                for (int r = 0; r < 4; r++) {
                    int row = mt * 16 + 4 * g + r;
                    if (row < 24)
                        out[OUT_TYPES + (size_t)(n0 + row) * 103 + a_col] = at2[mt][r] + bt;
                }
        }
    }
    // coords: 24x3 dots over K=256
    if (tid < 72) {
        int p = tid / 3, cc = tid % 3;
        float a0 = 0.f;
        for (int k = 0; k < 256; k++) a0 += s_nf[p][k] * w_coord[cc * 256 + k];
        out[OUT_COORD + (size_t)(n0 + p) * 3 + cc] = a0;
    }
    // gfeat mean
    if (tid < 256) {
        float s = 0.f;
#pragma unroll
        for (int i = 0; i < 24; i++) s += s_nf[i][tid];
        gf[tid] = s * (1.0f / 24.0f);
    }
    __syncthreads();
    if (tid < 9) {
        float a0 = 0.f;
        for (int k = 0; k < 256; k++) a0 += gf[k] * w_latt[tid * 256 + k];
        lo[tid] = a0;
    }
    __syncthreads();
    if (tid < 9) {
        int i = tid / 3, kk = tid % 3;
        float a0 = 0.f;
#pragma unroll
        for (int j = 0; j < 3; j++) a0 += lo[i * 3 + j] * lattices[b * 9 + j * 3 + kk];
        out[OUT_LATT + (size_t)b * 9 + tid] = a0;
    }
}

extern "C" void kernel_launch(void* const* d_in, const int* in_sizes, int n_in,
                              void* d_out, int out_size, void* d_ws, size_t ws_size,
                              hipStream_t stream) {
    const float* atom_types = (const float*)d_in[0];
    const float* frac       = (const float*)d_in[1];
    const float* lattices   = (const float*)d_in[2];
    const float* t_in       = (const float*)d_in[3];
    const float* text       = (const float*)d_in[4];
    const float* w_emb      = (const float*)d_in[5];
    const float* b_emb      = (const float*)d_in[6];
    const float* w_cond     = (const float*)d_in[7];
    const float* b_cond     = (const float*)d_in[8];
    const float* w_proj     = (const float*)d_in[9];
    const float* b_proj     = (const float*)d_in[10];
    const float* film_g     = (const float*)d_in[11];
    const float* film_b     = (const float*)d_in[12];
    const float* ew1        = (const float*)d_in[13];
    const float* eb1        = (const float*)d_in[14];
    const float* ew2        = (const float*)d_in[15];
    const float* eb2        = (const float*)d_in[16];
    const float* nw1        = (const float*)d_in[17];
    const float* nb1        = (const float*)d_in[18];
    const float* nw2        = (const float*)d_in[19];
    const float* nb2        = (const float*)d_in[20];
    const float* w_coord    = (const float*)d_in[21];
    const float* w_latt     = (const float*)d_in[22];
    const float* w_type     = (const float*)d_in[23];
    const float* b_type     = (const float*)d_in[24];
    float* ws  = (float*)d_ws;
    float* out = (float*)d_out;

    k_prep<<<7700, 256, 0, stream>>>(w_emb, w_cond, w_proj, ew1, ew2, nw1, nw2, w_type, ws);
    k_setup<<<8, 256, 0, stream>>>(lattices, t_in, text, b_cond, ws);
    for (int l = 0; l < NLAYERS; l++) {
        k_fnf<<<N_ / 16, 512, 0, stream>>>(l, atom_types, b_emb, nb1, nb2,
                                           b_proj, film_g, film_b, eb1, ws);
        k_edge<<<N_ * 12 / 24, 256, 0, stream>>>(l, frac, eb2, ws);
    }
    k_tail<<<B_, 512, 0, stream>>>(nb1, nb2, b_type, w_coord, lattices, w_latt, ws, out);
}